// Round 5
// baseline (818.218 us; speedup 1.0000x reference)
//
#include <hip/hip_runtime.h>
#include <hip/hip_bf16.h>

typedef __bf16 bf16x8 __attribute__((ext_vector_type(8)));
typedef _Float16 f16x4 __attribute__((ext_vector_type(4)));
typedef float f32x4 __attribute__((ext_vector_type(4)));

#define MFMA16(a, b, c) __builtin_amdgcn_mfma_f32_16x16x32_bf16(a, b, c, 0, 0, 0)
#define MFMA16H(a, b, c) __builtin_amdgcn_mfma_f32_16x16x16f16(a, b, c, 0, 0, 0)

#define T_SEQ 2048
#define D_MODEL 1024
#define N_HEADS 16
#define HEAD_DIM 64
#define D_FF 4096
#define QKV_STRIDE 3072

__device__ __forceinline__ float sigm(float x) { return 1.f / (1.f + __expf(-x)); }

// async global->LDS 16B copy; lds dst must be wave-uniform base + lane*16
__device__ __forceinline__ void g2l16(const void* g, void* l)
{
    __builtin_amdgcn_global_load_lds(
        (const __attribute__((address_space(1))) void*)g,
        (__attribute__((address_space(3))) void*)l, 16, 0, 0);
}

__device__ __forceinline__ float bperm(int srclane, float v)
{
    return __builtin_bit_cast(float,
        __builtin_amdgcn_ds_bpermute(srclane * 4, __builtin_bit_cast(int, v)));
}

// ---------------- fp32 -> bf16 cast, 8 elements/thread ----------------
__global__ __launch_bounds__(256) void cast_bf16_kernel(
    const float* __restrict__ in, __bf16* __restrict__ out, int n8)
{
    int i = blockIdx.x * blockDim.x + threadIdx.x;
    if (i >= n8) return;
    const float4* p = (const float4*)in + (size_t)i * 2;
    float4 a = p[0], b = p[1];
    union { __bf16 h[8]; float4 v; } u;
    u.h[0] = (__bf16)a.x; u.h[1] = (__bf16)a.y; u.h[2] = (__bf16)a.z; u.h[3] = (__bf16)a.w;
    u.h[4] = (__bf16)b.x; u.h[5] = (__bf16)b.y; u.h[6] = (__bf16)b.z; u.h[7] = (__bf16)b.w;
    ((float4*)out)[i] = u.v;
}

// ---------------- LayerNorm: fp32 in -> bf16 out ----------------
__global__ __launch_bounds__(256) void ln_kernel(
    const float* __restrict__ x, const float* __restrict__ g,
    const float* __restrict__ b, __bf16* __restrict__ out)
{
    const int t = blockIdx.x;
    const int tid = threadIdx.x;
    float4 xv = *(const float4*)&x[t * D_MODEL + tid * 4];
    float s = xv.x + xv.y + xv.z + xv.w;
    float ss = xv.x * xv.x + xv.y * xv.y + xv.z * xv.z + xv.w * xv.w;
    for (int off = 1; off < 64; off <<= 1) {
        s += __shfl_xor(s, off);
        ss += __shfl_xor(ss, off);
    }
    __shared__ float sb[8];
    int w = tid >> 6, lane = tid & 63;
    if (lane == 0) { sb[w] = s; sb[4 + w] = ss; }
    __syncthreads();
    s = sb[0] + sb[1] + sb[2] + sb[3];
    ss = sb[4] + sb[5] + sb[6] + sb[7];
    float mu = s * (1.f / D_MODEL);
    float var = ss * (1.f / D_MODEL) - mu * mu;
    float rs = rsqrtf(var + 1e-5f);
    const float* xp = (const float*)&xv;
    for (int i = 0; i < 4; ++i) {
        int d = tid * 4 + i;
        out[t * D_MODEL + d] = (__bf16)((xp[i] - mu) * rs * g[d] + b[d]);
    }
}

// ---------------- NT GEMM, BK=64 (two m97-layout half-tiles/iter) ----------
template<int BM, int EPI>
__global__ __launch_bounds__(256) void gemm_nt(
    const __bf16* __restrict__ A, const __bf16* __restrict__ B,
    const float* __restrict__ bias, const float* __restrict__ resid,
    __bf16* __restrict__ outb, float* __restrict__ outf,
    int M, int N, int K)
{
    constexpr int BN = 128;
    constexpr int EOUT = (EPI == 2) ? 4 : 2;
    constexpr int STAGE = (BM + BN) * 64 * 2;
    constexpr int CTB = BM * BN * EOUT;
    constexpr int SMEM = (STAGE > CTB) ? STAGE : CTB;
    __shared__ __align__(16) char smem[SMEM];
    __bf16* As = (__bf16*)smem;
    __bf16* Bs = As + BM * 64;

    const int tid = threadIdx.x;
    const int lane = tid & 63, w = tid >> 6;
    const int quad = lane >> 4, l16 = lane & 15;
    const int bm = blockIdx.x * BM, bn = blockIdx.y * BN;
    constexpr int NI = 4;
    constexpr int NJ = (BM == 128) ? 4 : 2;
    const int wm = (BM == 128) ? (w & 1) * 64 : 0;
    const int wn = (BM == 128) ? (w >> 1) * 64 : w * 32;

    f32x4 acc[NI][NJ] = {};

    for (int k0 = 0; k0 < K; k0 += 64) {
        __syncthreads();
        constexpr int AIT = BM * 8 / 256;
        for (int it = 0; it < AIT; ++it) {
            int c = it * 256 + tid;
            int tile = (c >= BM * 4) ? 1 : 0;
            int c2 = c & (BM * 4 - 1);
            g2l16(&A[(size_t)(bm + (c2 >> 2)) * K + k0 + tile * 32 + ((c2 & 3) << 3)],
                  &As[c * 8]);
        }
        for (int it = 0; it < 4; ++it) {
            int c = it * 256 + tid;
            int tile = (c >= 512) ? 1 : 0;
            int c2 = c & 511;
            g2l16(&B[(size_t)(bn + (c2 >> 2)) * K + k0 + tile * 32 + ((c2 & 3) << 3)],
                  &Bs[c * 8]);
        }
        __syncthreads();
        for (int ks = 0; ks < 2; ++ks) {
            bf16x8 af[NI], bfr[NJ];
            for (int i = 0; i < NI; ++i)
                af[i] = *(const bf16x8*)&As[ks * BM * 32 + (wm + i * 16 + l16) * 32 + quad * 8];
            for (int j = 0; j < NJ; ++j)
                bfr[j] = *(const bf16x8*)&Bs[ks * BN * 32 + (wn + j * 16 + l16) * 32 + quad * 8];
            for (int i = 0; i < NI; ++i)
                for (int j = 0; j < NJ; ++j)
                    acc[i][j] = MFMA16(af[i], bfr[j], acc[i][j]);
        }
    }

    __syncthreads();
    if (EPI == 2) {
        float* Ct = (float*)smem;
        for (int i = 0; i < NI; ++i)
            for (int j = 0; j < NJ; ++j)
                for (int r = 0; r < 4; ++r) {
                    int row = wm + i * 16 + quad * 4 + r;
                    int col = wn + j * 16 + l16;
                    float v = acc[i][j][r];
                    if (bias) v += bias[bn + col];
                    Ct[row * BN + col] = v;
                }
        __syncthreads();
        constexpr int IT = BM * BN / 4 / 256;
        for (int it = 0; it < IT; ++it) {
            int c = it * 256 + tid;
            int row = c >> 5, col = (c & 31) << 2;
            float4 v = *(float4*)&Ct[row * BN + col];
            size_t gi = (size_t)(bm + row) * N + bn + col;
            float4 r4 = *(const float4*)&resid[gi];
            v.x += r4.x; v.y += r4.y; v.z += r4.z; v.w += r4.w;
            *(float4*)&outf[gi] = v;
        }
    } else {
        __bf16* Ct = (__bf16*)smem;
        for (int i = 0; i < NI; ++i)
            for (int j = 0; j < NJ; ++j)
                for (int r = 0; r < 4; ++r) {
                    int row = wm + i * 16 + quad * 4 + r;
                    int col = wn + j * 16 + l16;
                    float v = acc[i][j][r];
                    if (bias) v += bias[bn + col];
                    if (EPI == 1) v = 0.5f * v * (1.f + erff(v * 0.70710678118f));
                    Ct[row * BN + col] = (__bf16)v;
                }
        __syncthreads();
        constexpr int IT = BM * BN / 8 / 256;
        for (int it = 0; it < IT; ++it) {
            int c = it * 256 + tid;
            int row = c >> 4, col = (c & 15) << 3;
            *(float4*)&outb[(size_t)(bm + row) * N + bn + col] = *(float4*)&Ct[row * BN + col];
        }
    }
}

// ---------------- V transpose: qkv bf16 -> vt[h][dh][t] f16 ----------------
__global__ __launch_bounds__(256) void vtrans_kernel(
    const __bf16* __restrict__ qkv, _Float16* __restrict__ vt)
{
    __shared__ __bf16 Vl[64 * 72];
    const int t0 = blockIdx.x * 64, h = blockIdx.y;
    const int tid = threadIdx.x;
    for (int it = 0; it < 2; ++it) {
        int c = it * 256 + tid;
        int row = c >> 3, col8 = (c & 7) << 3;
        *(float4*)&Vl[row * 72 + col8] =
            *(const float4*)&qkv[(size_t)(t0 + row) * QKV_STRIDE + 2048 + h * 64 + col8];
    }
    __syncthreads();
    int d = tid >> 2, tseg = (tid & 3) << 4;
    _Float16 buf[16];
    for (int i = 0; i < 16; ++i)
        buf[i] = (_Float16)(float)Vl[(tseg + i) * 72 + d];
    _Float16* dst = &vt[((size_t)h * 64 + d) * T_SEQ + t0 + tseg];
    *(float4*)&dst[0] = *(float4*)&buf[0];
    *(float4*)&dst[8] = *(float4*)&buf[8];
}

// ---------------- split-s dual-variant flash attention (S^T scheme) -------
// S^T = K·Q^T lands P in 16x16x16-f16 A-operand layout -> PV with no LDS
// round-trip. V pre-transposed globally; staged with XOR-granule swizzle.
__global__ __launch_bounds__(256) void attn_split_kernel(
    const __bf16* __restrict__ qkv, const _Float16* __restrict__ vt,
    const float* __restrict__ lmask,
    __bf16* __restrict__ part_O, float2* __restrict__ part_ml,
    float* __restrict__ sigacc)
{
    __shared__ __bf16 Ks[2 * 64 * 32];   // two [64 s][32 d] half-tiles, 8 KB
    __shared__ _Float16 Vs[64 * 64];     // [dh][64 s], granule-swizzled, 8 KB

    const int tid = threadIdx.x;
    const int w = tid >> 6, lane = tid & 63;
    const int quad = lane >> 4, l16 = lane & 15;
    const int idx = blockIdx.x, h = blockIdx.y;
    int qt, sp;
    if (idx < 8)       { qt = idx;                sp = 0; }
    else if (idx < 24) { qt = 8 + ((idx - 8) >> 1);  sp = (idx - 8) & 1; }
    else if (idx < 48) { qt = 16 + (idx - 24) / 3;   sp = (idx - 24) % 3; }
    else               { qt = 24 + ((idx - 48) >> 2); sp = (idx - 48) & 3; }
    const int q0 = qt * 64;
    const int sbeg = sp * 512;
    const int send = min(sbeg + 512, q0 + 64);

    const int tq = q0 + w * 16 + l16;      // this lane's q column
    bf16x8 qf0 = *(const bf16x8*)&qkv[(size_t)tq * QKV_STRIDE + h * 64 + quad * 8];
    bf16x8 qf1 = *(const bf16x8*)&qkv[(size_t)tq * QKV_STRIDE + h * 64 + 32 + quad * 8];

    float m_[2] = {-1e30f, -1e30f}, l_[2] = {0.f, 0.f};
    f32x4 O[2][4] = {};
    float sigsum = 0.f;

    for (int s0 = sbeg; s0 < send; s0 += 64) {
        // lmask: 4 contiguous fp32 per tile (q=l16 row, s runs in-register)
        float4 lm[4];
        for (int c = 0; c < 4; ++c)
            lm[c] = *(const float4*)&lmask[((size_t)h * T_SEQ + tq) * T_SEQ + s0 + c * 16 + quad * 4];
        __syncthreads();
        // K tile: async, m97 layout
        for (int it = 0; it < 2; ++it) {
            int c = it * 256 + tid;
            int tile = c >> 8, c2 = c & 255;
            g2l16(&qkv[(size_t)(s0 + (c2 >> 2)) * QKV_STRIDE + 1024 + h * 64 + tile * 32 + ((c2 & 3) << 3)],
                  &Ks[c * 8]);
        }
        // V tile: async from vt, granule-swizzled (granule g of row dh holds
        // s-segment ((g+dh)&7)*8) for conflict-free b64 fragment reads
        for (int it = 0; it < 2; ++it) {
            int c = it * 256 + tid;
            int dh = c >> 3, g = c & 7;
            int sIn = ((g + dh) & 7) * 8;
            g2l16(&vt[((size_t)h * 64 + dh) * T_SEQ + s0 + sIn], &Vs[c * 8]);
        }
        __syncthreads();

        // S^T tiles: C-layout element (s=quad*4+r, q=l16)
        f32x4 St[4];
        for (int c = 0; c < 4; ++c) {
            bf16x8 kf0 = *(const bf16x8*)&Ks[(c * 16 + l16) * 32 + quad * 8];
            bf16x8 kf1 = *(const bf16x8*)&Ks[2048 + (c * 16 + l16) * 32 + quad * 8];
            f32x4 z = {};
            z = MFMA16(kf0, qf0, z);
            z = MFMA16(kf1, qf1, z);
            St[c] = z * 0.125f;
        }
        // V fragments: B[n=dh][k=s], half4 via swizzled b64 reads
        f16x4 vf[4][4];
        for (int c = 0; c < 4; ++c)
            for (int j = 0; j < 4; ++j) {
                int dh = j * 16 + l16;
                int gg = ((2 * c + (quad >> 1)) - dh) & 7;
                vf[c][j] = *(const f16x4*)&Vs[dh * 64 + gg * 8 + (quad & 1) * 4];
            }
        float sg[4][4];
        for (int c = 0; c < 4; ++c) {
            const float* lp = (const float*)&lm[c];
            for (int r = 0; r < 4; ++r) { sg[c][r] = sigm(lp[r]); sigsum += sg[c][r]; }
        }

        for (int v = 0; v < 2; ++v) {
            float p[4][4];
            float mx = -1e30f;
            for (int c = 0; c < 4; ++c) {
                int sbase = s0 + c * 16 + quad * 4;
                for (int r = 0; r < 4; ++r) {
                    float val = v ? St[c][r] * sg[c][r] : St[c][r];
                    val = (sbase + r > tq) ? -1e30f : val;
                    p[c][r] = val;
                    mx = fmaxf(mx, val);
                }
            }
            mx = fmaxf(mx, __shfl_xor(mx, 16));
            mx = fmaxf(mx, __shfl_xor(mx, 32));
            float mn = fmaxf(m_[v], mx);
            float al = __expf(m_[v] - mn);
            m_[v] = mn;
            float rs = 0.f;
            f16x4 pa[4];
            for (int c = 0; c < 4; ++c)
                for (int r = 0; r < 4; ++r) {
                    float e = __expf(p[c][r] - mn);
                    rs += e;
                    pa[c][r] = (_Float16)e;
                }
            rs += __shfl_xor(rs, 16);
            rs += __shfl_xor(rs, 32);
            l_[v] = l_[v] * al + rs;
            // move rescale factor into O orientation (q=quad*4+r)
            float alO[4];
            for (int r = 0; r < 4; ++r) alO[r] = bperm(quad * 4 + r, al);
            for (int j = 0; j < 4; ++j)
                for (int r = 0; r < 4; ++r) O[v][j][r] *= alO[r];
            for (int c = 0; c < 4; ++c)
                for (int j = 0; j < 4; ++j)
                    O[v][j] = MFMA16H(pa[c], vf[c][j], O[v][j]);
        }
    }

    const size_t slot = (size_t)h * 80 + idx;
    for (int v = 0; v < 2; ++v)
        for (int j = 0; j < 4; ++j)
            for (int r = 0; r < 4; ++r) {
                int row = w * 16 + quad * 4 + r;
                part_O[((slot * 2 + v) * 64 + row) * 64 + j * 16 + l16] = (__bf16)O[v][j][r];
            }
    if (quad == 0)
        for (int v = 0; v < 2; ++v)
            part_ml[(slot * 2 + v) * 64 + w * 16 + l16] = make_float2(m_[v], l_[v]);
    for (int off = 1; off < 64; off <<= 1) sigsum += __shfl_xor(sigsum, off);
    if (lane == 0) atomicAdd(sigacc, sigsum);
}

// ---------------- combine partials -> cat ----------------
__global__ __launch_bounds__(256) void attn_combine_kernel(
    const __bf16* __restrict__ part_O, const float2* __restrict__ part_ml,
    __bf16* __restrict__ cat)
{
    const int qt = blockIdx.x, h = blockIdx.y;
    const int nsp = (qt >> 3) + 1;
    const int base = (qt < 8) ? qt : (qt < 16) ? 8 + (qt - 8) * 2
                   : (qt < 24) ? 24 + (qt - 16) * 3 : 48 + (qt - 24) * 4;
    const int tid = threadIdx.x;
    const int row = tid >> 2, v = (tid >> 1) & 1, colh = (tid & 1) * 32;

    float2 ml[4];
    float M = -1e30f;
    for (int p = 0; p < nsp; ++p) {
        ml[p] = part_ml[(((size_t)h * 80 + base + p) * 2 + v) * 64 + row];
        M = fmaxf(M, ml[p].x);
    }
    float L = 0.f;
    float acc[32] = {};
    for (int p = 0; p < nsp; ++p) {
        float sc = __expf(ml[p].x - M);
        L += sc * ml[p].y;
        const __bf16* src =
            &part_O[((((size_t)h * 80 + base + p) * 2 + v) * 64 + row) * 64 + colh];
        for (int k = 0; k < 4; ++k) {
            bf16x8 o = *(const bf16x8*)&src[k * 8];
            for (int e = 0; e < 8; ++e) acc[k * 8 + e] += sc * (float)o[e];
        }
    }
    float inv = 1.f / L;
    __bf16* dst = &cat[(size_t)(qt * 64 + row) * 2048 + v * 1024 + h * 64 + colh];
    for (int k = 0; k < 4; ++k) {
        union { __bf16 hh[8]; float4 f4; } u;
        for (int e = 0; e < 8; ++e) u.hh[e] = (__bf16)(acc[k * 8 + e] * inv);
        *(float4*)&dst[k * 8] = u.f4;
    }
}

// ---------------- sigmoid-sum over strict upper tiles ----------------
__global__ void zero_acc_kernel(float* acc) { acc[0] = 0.f; }

__global__ __launch_bounds__(256) void sigmean_upper_kernel(
    const float* __restrict__ lm, float* __restrict__ acc)
{
    const int qt = blockIdx.x, h = blockIdx.y, rg = blockIdx.z;
    const int sc0 = (qt + 1) * 64;
    const int len4 = (T_SEQ - sc0) >> 2;
    float s = 0.f;
    for (int r = 0; r < 16; ++r) {
        const float* rowp = &lm[((size_t)h * T_SEQ + qt * 64 + rg * 16 + r) * T_SEQ + sc0];
        for (int c = threadIdx.x; c < len4; c += 256) {
            float4 a = *(const float4*)&rowp[c * 4];
            s += sigm(a.x) + sigm(a.y) + sigm(a.z) + sigm(a.w);
        }
    }
    for (int off = 1; off < 64; off <<= 1) s += __shfl_xor(s, off);
    if ((threadIdx.x & 63) == 0) atomicAdd(acc, s);
}

__global__ void write_sp_kernel(const float* __restrict__ acc, float* __restrict__ out)
{
    out[(size_t)T_SEQ * D_MODEL] = 0.0005f * acc[0] * (1.f / 67108864.f);
}

// ---------------- launch ----------------
extern "C" void kernel_launch(void* const* d_in, const int* in_sizes, int n_in,
                              void* d_out, int out_size, void* d_ws, size_t ws_size,
                              hipStream_t stream)
{
    const float* x      = (const float*)d_in[0];
    const float* W_qkv  = (const float*)d_in[2];
    const float* W_out  = (const float*)d_in[3];
    const float* lmask  = (const float*)d_in[4];
    const float* W_gate = (const float*)d_in[5];
    const float* b_gate = (const float*)d_in[6];
    const float* g1     = (const float*)d_in[7];
    const float* b1     = (const float*)d_in[8];
    const float* g2     = (const float*)d_in[9];
    const float* b2     = (const float*)d_in[10];
    const float* W_ff1  = (const float*)d_in[11];
    const float* b_ff1  = (const float*)d_in[12];
    const float* W_ff2  = (const float*)d_in[13];
    const float* b_ff2  = (const float*)d_in[14];
    float* out = (float*)d_out;

    char* ws = (char*)d_ws;
    size_t off = 0;
    auto alloc = [&](size_t bytes) {
        char* p = ws + off;
        off += (bytes + 255) & ~(size_t)255;
        return p;
    };
    __bf16* wq_b   = (__bf16*)alloc((size_t)3072 * 1024 * 2);
    __bf16* wout_b = (__bf16*)alloc((size_t)1024 * 1024 * 2);
    __bf16* wg_b   = (__bf16*)alloc((size_t)1024 * 2048 * 2);
    __bf16* wf1_b  = (__bf16*)alloc((size_t)4096 * 1024 * 2);
    __bf16* wf2_b  = (__bf16*)alloc((size_t)1024 * 4096 * 2);
    __bf16* xn_b   = (__bf16*)alloc((size_t)2048 * 1024 * 2);
    __bf16* qkv_b  = (__bf16*)alloc((size_t)2048 * 3072 * 2);
    _Float16* vt_h = (_Float16*)alloc((size_t)16 * 64 * 2048 * 2);
    __bf16* cat_b  = (__bf16*)alloc((size_t)2048 * 2048 * 2);
    __bf16* a1_b   = (__bf16*)alloc((size_t)2048 * 1024 * 2);
    float*  h_f    = (float*)alloc((size_t)2048 * 1024 * 4);
    __bf16* hn_b   = (__bf16*)alloc((size_t)2048 * 1024 * 2);
    __bf16* e_b    = (__bf16*)alloc((size_t)2048 * 4096 * 2);
    __bf16* part_O = (__bf16*)alloc((size_t)16 * 80 * 2 * 64 * 64 * 2);
    float2* part_ml= (float2*)alloc((size_t)16 * 80 * 2 * 64 * 8);
    float*  acc    = (float*)alloc(256);

    zero_acc_kernel<<<1, 1, 0, stream>>>(acc);

    cast_bf16_kernel<<<(3072 * 1024 / 8 + 255) / 256, 256, 0, stream>>>(W_qkv, wq_b, 3072 * 1024 / 8);
    cast_bf16_kernel<<<(1024 * 1024 / 8 + 255) / 256, 256, 0, stream>>>(W_out, wout_b, 1024 * 1024 / 8);
    cast_bf16_kernel<<<(1024 * 2048 / 8 + 255) / 256, 256, 0, stream>>>(W_gate, wg_b, 1024 * 2048 / 8);
    cast_bf16_kernel<<<(4096 * 1024 / 8 + 255) / 256, 256, 0, stream>>>(W_ff1, wf1_b, 4096 * 1024 / 8);
    cast_bf16_kernel<<<(1024 * 4096 / 8 + 255) / 256, 256, 0, stream>>>(W_ff2, wf2_b, 1024 * 4096 / 8);

    ln_kernel<<<2048, 256, 0, stream>>>(x, g1, b1, xn_b);
    gemm_nt<128, 0><<<dim3(16, 24), 256, 0, stream>>>(xn_b, wq_b, nullptr, nullptr, qkv_b, nullptr, 2048, 3072, 1024);
    vtrans_kernel<<<dim3(32, 16), 256, 0, stream>>>(qkv_b, vt_h);
    attn_split_kernel<<<dim3(80, 16), 256, 0, stream>>>(qkv_b, vt_h, lmask, part_O, part_ml, acc);
    attn_combine_kernel<<<dim3(32, 16), 256, 0, stream>>>(part_O, part_ml, cat_b);
    sigmean_upper_kernel<<<dim3(32, 16, 4), 256, 0, stream>>>(lmask, acc);

    gemm_nt<64, 0><<<dim3(32, 8), 256, 0, stream>>>(cat_b, wg_b, b_gate, nullptr, a1_b, nullptr, 2048, 1024, 2048);
    gemm_nt<64, 2><<<dim3(32, 8), 256, 0, stream>>>(a1_b, wout_b, nullptr, x, nullptr, h_f, 2048, 1024, 1024);
    ln_kernel<<<2048, 256, 0, stream>>>(h_f, g2, b2, hn_b);
    gemm_nt<128, 1><<<dim3(16, 32), 256, 0, stream>>>(hn_b, wf1_b, b_ff1, nullptr, e_b, nullptr, 2048, 4096, 1024);
    gemm_nt<64, 2><<<dim3(32, 8), 256, 0, stream>>>(e_b, wf2_b, b_ff2, h_f, nullptr, out, 2048, 1024, 4096);

    write_sp_kernel<<<1, 1, 0, stream>>>(acc, out);

    (void)in_sizes; (void)n_in; (void)out_size; (void)ws_size;
}

// Round 6
// 782.539 us; speedup vs baseline: 1.0456x; 1.0456x over previous
//
#include <hip/hip_runtime.h>
#include <hip/hip_bf16.h>

typedef __bf16 bf16x8 __attribute__((ext_vector_type(8)));
typedef _Float16 f16x4 __attribute__((ext_vector_type(4)));
typedef float f32x4 __attribute__((ext_vector_type(4)));

#define MFMA16(a, b, c) __builtin_amdgcn_mfma_f32_16x16x32_bf16(a, b, c, 0, 0, 0)
#define MFMA16H(a, b, c) __builtin_amdgcn_mfma_f32_16x16x16f16(a, b, c, 0, 0, 0)

#define T_SEQ 2048
#define D_MODEL 1024
#define N_HEADS 16
#define HEAD_DIM 64
#define D_FF 4096
#define QKV_STRIDE 3072

__device__ __forceinline__ float sigm(float x) { return 1.f / (1.f + __expf(-x)); }

// async global->LDS 16B copy; lds dst must be wave-uniform base + lane*16
__device__ __forceinline__ void g2l16(const void* g, void* l)
{
    __builtin_amdgcn_global_load_lds(
        (const __attribute__((address_space(1))) void*)g,
        (__attribute__((address_space(3))) void*)l, 16, 0, 0);
}

__device__ __forceinline__ float bperm(int srclane, float v)
{
    return __builtin_bit_cast(float,
        __builtin_amdgcn_ds_bpermute(srclane * 4, __builtin_bit_cast(int, v)));
}

// ---------------- all weight casts fused: fp32 -> bf16, 8 elem/thread ------
#define N8_QKV 393216
#define N8_OUT 131072
#define N8_GATE 262144
#define N8_FF1 524288
#define N8_FF2 524288
__global__ __launch_bounds__(256) void cast_all_kernel(
    const float* __restrict__ s0, const float* __restrict__ s1,
    const float* __restrict__ s2, const float* __restrict__ s3,
    const float* __restrict__ s4,
    __bf16* __restrict__ d0, __bf16* __restrict__ d1, __bf16* __restrict__ d2,
    __bf16* __restrict__ d3, __bf16* __restrict__ d4)
{
    int i = blockIdx.x * 256 + threadIdx.x;
    const float* s; __bf16* d; int j;
    if (i < N8_QKV)                           { s = s0; d = d0; j = i; }
    else if (i < N8_QKV + N8_OUT)             { s = s1; d = d1; j = i - N8_QKV; }
    else if (i < N8_QKV + N8_OUT + N8_GATE)   { s = s2; d = d2; j = i - N8_QKV - N8_OUT; }
    else if (i < N8_QKV + N8_OUT + N8_GATE + N8_FF1)
        { s = s3; d = d3; j = i - N8_QKV - N8_OUT - N8_GATE; }
    else { s = s4; d = d4; j = i - N8_QKV - N8_OUT - N8_GATE - N8_FF1; }
    const float4* p = (const float4*)s + (size_t)j * 2;
    float4 a = p[0], b = p[1];
    union { __bf16 h[8]; float4 v; } u;
    u.h[0] = (__bf16)a.x; u.h[1] = (__bf16)a.y; u.h[2] = (__bf16)a.z; u.h[3] = (__bf16)a.w;
    u.h[4] = (__bf16)b.x; u.h[5] = (__bf16)b.y; u.h[6] = (__bf16)b.z; u.h[7] = (__bf16)b.w;
    ((float4*)d)[j] = u.v;
}

// ---------------- LayerNorm: fp32 in -> bf16 out ----------------
__global__ __launch_bounds__(256) void ln_kernel(
    const float* __restrict__ x, const float* __restrict__ g,
    const float* __restrict__ b, __bf16* __restrict__ out)
{
    const int t = blockIdx.x;
    const int tid = threadIdx.x;
    float4 xv = *(const float4*)&x[t * D_MODEL + tid * 4];
    float s = xv.x + xv.y + xv.z + xv.w;
    float ss = xv.x * xv.x + xv.y * xv.y + xv.z * xv.z + xv.w * xv.w;
    for (int off = 1; off < 64; off <<= 1) {
        s += __shfl_xor(s, off);
        ss += __shfl_xor(ss, off);
    }
    __shared__ float sb[8];
    int w = tid >> 6, lane = tid & 63;
    if (lane == 0) { sb[w] = s; sb[4 + w] = ss; }
    __syncthreads();
    s = sb[0] + sb[1] + sb[2] + sb[3];
    ss = sb[4] + sb[5] + sb[6] + sb[7];
    float mu = s * (1.f / D_MODEL);
    float var = ss * (1.f / D_MODEL) - mu * mu;
    float rs = rsqrtf(var + 1e-5f);
    const float* xp = (const float*)&xv;
    for (int i = 0; i < 4; ++i) {
        int d = tid * 4 + i;
        out[t * D_MODEL + d] = (__bf16)((xp[i] - mu) * rs * g[d] + b[d]);
    }
}

// ---------------- NT GEMM, BK=64, optional split-K via blockIdx.z ----------
// EPI 0: bf16 out (+opt bias); EPI 1: bias + exact GELU -> bf16;
// EPI 3: fp32 partial (split-K slice z writes outf + z*M*N).
template<int BM, int EPI>
__global__ __launch_bounds__(256) void gemm_nt(
    const __bf16* __restrict__ A, const __bf16* __restrict__ B,
    const float* __restrict__ bias,
    __bf16* __restrict__ outb, float* __restrict__ outf,
    int M, int N, int klen, int lda)
{
    constexpr int BN = 128;
    constexpr int EOUT = (EPI == 3) ? 4 : 2;
    constexpr int STAGE = (BM + BN) * 64 * 2;
    constexpr int CTB = BM * BN * EOUT;
    constexpr int SMEM = (STAGE > CTB) ? STAGE : CTB;
    __shared__ __align__(16) char smem[SMEM];
    __bf16* As = (__bf16*)smem;
    __bf16* Bs = As + BM * 64;

    const int tid = threadIdx.x;
    const int lane = tid & 63, w = tid >> 6;
    const int quad = lane >> 4, l16 = lane & 15;
    const int bm = blockIdx.x * BM, bn = blockIdx.y * BN;
    const int koff = blockIdx.z * klen;
    if (EPI == 3) outf += (size_t)blockIdx.z * M * N;
    constexpr int NI = 4;
    constexpr int NJ = (BM == 128) ? 4 : 2;
    const int wm = (BM == 128) ? (w & 1) * 64 : 0;
    const int wn = (BM == 128) ? (w >> 1) * 64 : w * 32;

    f32x4 acc[NI][NJ] = {};

    for (int k0 = 0; k0 < klen; k0 += 64) {
        __syncthreads();
        constexpr int AIT = BM * 8 / 256;
        for (int it = 0; it < AIT; ++it) {
            int c = it * 256 + tid;
            int tile = (c >= BM * 4) ? 1 : 0;
            int c2 = c & (BM * 4 - 1);
            g2l16(&A[(size_t)(bm + (c2 >> 2)) * lda + koff + k0 + tile * 32 + ((c2 & 3) << 3)],
                  &As[c * 8]);
        }
        for (int it = 0; it < 4; ++it) {
            int c = it * 256 + tid;
            int tile = (c >= 512) ? 1 : 0;
            int c2 = c & 511;
            g2l16(&B[(size_t)(bn + (c2 >> 2)) * lda + koff + k0 + tile * 32 + ((c2 & 3) << 3)],
                  &Bs[c * 8]);
        }
        __syncthreads();
        for (int ks = 0; ks < 2; ++ks) {
            bf16x8 af[NI], bfr[NJ];
            for (int i = 0; i < NI; ++i)
                af[i] = *(const bf16x8*)&As[ks * BM * 32 + (wm + i * 16 + l16) * 32 + quad * 8];
            for (int j = 0; j < NJ; ++j)
                bfr[j] = *(const bf16x8*)&Bs[ks * BN * 32 + (wn + j * 16 + l16) * 32 + quad * 8];
            for (int i = 0; i < NI; ++i)
                for (int j = 0; j < NJ; ++j)
                    acc[i][j] = MFMA16(af[i], bfr[j], acc[i][j]);
        }
    }

    __syncthreads();
    if (EPI == 3) {
        float* Ct = (float*)smem;
        for (int i = 0; i < NI; ++i)
            for (int j = 0; j < NJ; ++j)
                for (int r = 0; r < 4; ++r)
                    Ct[(wm + i * 16 + quad * 4 + r) * BN + wn + j * 16 + l16] = acc[i][j][r];
        __syncthreads();
        constexpr int IT = BM * BN / 4 / 256;
        for (int it = 0; it < IT; ++it) {
            int c = it * 256 + tid;
            int row = c >> 5, col = (c & 31) << 2;
            *(float4*)&outf[(size_t)(bm + row) * N + bn + col] = *(float4*)&Ct[row * BN + col];
        }
    } else {
        __bf16* Ct = (__bf16*)smem;
        for (int i = 0; i < NI; ++i)
            for (int j = 0; j < NJ; ++j)
                for (int r = 0; r < 4; ++r) {
                    int row = wm + i * 16 + quad * 4 + r;
                    int col = wn + j * 16 + l16;
                    float v = acc[i][j][r];
                    if (bias) v += bias[bn + col];
                    if (EPI == 1) v = 0.5f * v * (1.f + erff(v * 0.70710678118f));
                    Ct[row * BN + col] = (__bf16)v;
                }
        __syncthreads();
        constexpr int IT = BM * BN / 8 / 256;
        for (int it = 0; it < IT; ++it) {
            int c = it * 256 + tid;
            int row = c >> 4, col = (c & 15) << 3;
            *(float4*)&outb[(size_t)(bm + row) * N + bn + col] = *(float4*)&Ct[row * BN + col];
        }
    }
}

// ---------------- split-K combine (N=1024 fixed) ----------------
// MODE 0: bf16(p0+p1+bias); MODE 1: fp32 p0+p1+resid; MODE 2: fp32 p0+p1+bias+resid
template<int MODE>
__global__ __launch_bounds__(256) void combine_kernel(
    const float* __restrict__ p0, const float* __restrict__ p1,
    const float* __restrict__ bias, const float* __restrict__ resid,
    __bf16* __restrict__ outb, float* __restrict__ outf)
{
    int i = blockIdx.x * 256 + threadIdx.x;   // float4 index over M*N/4
    float4 a = ((const float4*)p0)[i];
    float4 b = ((const float4*)p1)[i];
    float v[4] = {a.x + b.x, a.y + b.y, a.z + b.z, a.w + b.w};
    if (MODE == 0 || MODE == 2) {
        int col = (i & 255) << 2;
        float4 bb = *(const float4*)&bias[col];
        v[0] += bb.x; v[1] += bb.y; v[2] += bb.z; v[3] += bb.w;
    }
    if (MODE >= 1) {
        float4 r = ((const float4*)resid)[i];
        v[0] += r.x; v[1] += r.y; v[2] += r.z; v[3] += r.w;
    }
    if (MODE == 0) {
        union { __bf16 h[4]; float2 f2; } u;
        for (int e = 0; e < 4; ++e) u.h[e] = (__bf16)v[e];
        ((float2*)outb)[i] = u.f2;
    } else {
        float4 o = {v[0], v[1], v[2], v[3]};
        ((float4*)outf)[i] = o;
    }
}

// ---------------- V transpose: qkv bf16 -> vt[h][dh][t] f16 ----------------
__global__ __launch_bounds__(256) void vtrans_kernel(
    const __bf16* __restrict__ qkv, _Float16* __restrict__ vt)
{
    __shared__ __bf16 Vl[64 * 72];
    const int t0 = blockIdx.x * 64, h = blockIdx.y;
    const int tid = threadIdx.x;
    for (int it = 0; it < 2; ++it) {
        int c = it * 256 + tid;
        int row = c >> 3, col8 = (c & 7) << 3;
        *(float4*)&Vl[row * 72 + col8] =
            *(const float4*)&qkv[(size_t)(t0 + row) * QKV_STRIDE + 2048 + h * 64 + col8];
    }
    __syncthreads();
    int d = tid >> 2, tseg = (tid & 3) << 4;
    _Float16 buf[16];
    for (int i = 0; i < 16; ++i)
        buf[i] = (_Float16)(float)Vl[(tseg + i) * 72 + d];
    _Float16* dst = &vt[((size_t)h * 64 + d) * T_SEQ + t0 + tseg];
    *(float4*)&dst[0] = *(float4*)&buf[0];
    *(float4*)&dst[8] = *(float4*)&buf[8];
}

// ---------------- split-s dual-variant flash attention (S^T scheme) -------
__global__ __launch_bounds__(256) void attn_split_kernel(
    const __bf16* __restrict__ qkv, const _Float16* __restrict__ vt,
    const float* __restrict__ lmask,
    __bf16* __restrict__ part_O, float2* __restrict__ part_ml,
    float* __restrict__ sigacc)
{
    __shared__ __bf16 Ks[2 * 64 * 32];
    __shared__ _Float16 Vs[64 * 64];

    const int tid = threadIdx.x;
    const int w = tid >> 6, lane = tid & 63;
    const int quad = lane >> 4, l16 = lane & 15;
    const int idx = blockIdx.x, h = blockIdx.y;
    int qt, sp;
    if (idx < 8)       { qt = idx;                sp = 0; }
    else if (idx < 24) { qt = 8 + ((idx - 8) >> 1);  sp = (idx - 8) & 1; }
    else if (idx < 48) { qt = 16 + (idx - 24) / 3;   sp = (idx - 24) % 3; }
    else               { qt = 24 + ((idx - 48) >> 2); sp = (idx - 48) & 3; }
    const int q0 = qt * 64;
    const int sbeg = sp * 512;
    const int send = min(sbeg + 512, q0 + 64);

    const int tq = q0 + w * 16 + l16;
    bf16x8 qf0 = *(const bf16x8*)&qkv[(size_t)tq * QKV_STRIDE + h * 64 + quad * 8];
    bf16x8 qf1 = *(const bf16x8*)&qkv[(size_t)tq * QKV_STRIDE + h * 64 + 32 + quad * 8];

    float m_[2] = {-1e30f, -1e30f}, l_[2] = {0.f, 0.f};
    f32x4 O[2][4] = {};
    float sigsum = 0.f;

    for (int s0 = sbeg; s0 < send; s0 += 64) {
        float4 lm[4];
        for (int c = 0; c < 4; ++c)
            lm[c] = *(const float4*)&lmask[((size_t)h * T_SEQ + tq) * T_SEQ + s0 + c * 16 + quad * 4];
        __syncthreads();
        for (int it = 0; it < 2; ++it) {
            int c = it * 256 + tid;
            int tile = c >> 8, c2 = c & 255;
            g2l16(&qkv[(size_t)(s0 + (c2 >> 2)) * QKV_STRIDE + 1024 + h * 64 + tile * 32 + ((c2 & 3) << 3)],
                  &Ks[c * 8]);
        }
        for (int it = 0; it < 2; ++it) {
            int c = it * 256 + tid;
            int dh = c >> 3, g = c & 7;
            int sIn = ((g + dh) & 7) * 8;
            g2l16(&vt[((size_t)h * 64 + dh) * T_SEQ + s0 + sIn], &Vs[c * 8]);
        }
        __syncthreads();

        f32x4 St[4];
        for (int c = 0; c < 4; ++c) {
            bf16x8 kf0 = *(const bf16x8*)&Ks[(c * 16 + l16) * 32 + quad * 8];
            bf16x8 kf1 = *(const bf16x8*)&Ks[2048 + (c * 16 + l16) * 32 + quad * 8];
            f32x4 z = {};
            z = MFMA16(kf0, qf0, z);
            z = MFMA16(kf1, qf1, z);
            St[c] = z * 0.125f;
        }
        f16x4 vf[4][4];
        for (int c = 0; c < 4; ++c)
            for (int j = 0; j < 4; ++j) {
                int dh = j * 16 + l16;
                int gg = ((2 * c + (quad >> 1)) - dh) & 7;
                vf[c][j] = *(const f16x4*)&Vs[dh * 64 + gg * 8 + (quad & 1) * 4];
            }
        float sg[4][4];
        for (int c = 0; c < 4; ++c) {
            const float* lp = (const float*)&lm[c];
            for (int r = 0; r < 4; ++r) { sg[c][r] = sigm(lp[r]); sigsum += sg[c][r]; }
        }

        for (int v = 0; v < 2; ++v) {
            float p[4][4];
            float mx = -1e30f;
            for (int c = 0; c < 4; ++c) {
                int sbase = s0 + c * 16 + quad * 4;
                for (int r = 0; r < 4; ++r) {
                    float val = v ? St[c][r] * sg[c][r] : St[c][r];
                    val = (sbase + r > tq) ? -1e30f : val;
                    p[c][r] = val;
                    mx = fmaxf(mx, val);
                }
            }
            mx = fmaxf(mx, __shfl_xor(mx, 16));
            mx = fmaxf(mx, __shfl_xor(mx, 32));
            float mn = fmaxf(m_[v], mx);
            float al = __expf(m_[v] - mn);
            m_[v] = mn;
            float rs = 0.f;
            f16x4 pa[4];
            for (int c = 0; c < 4; ++c)
                for (int r = 0; r < 4; ++r) {
                    float e = __expf(p[c][r] - mn);
                    rs += e;
                    pa[c][r] = (_Float16)e;
                }
            rs += __shfl_xor(rs, 16);
            rs += __shfl_xor(rs, 32);
            l_[v] = l_[v] * al + rs;
            float alO[4];
            for (int r = 0; r < 4; ++r) alO[r] = bperm(quad * 4 + r, al);
            for (int j = 0; j < 4; ++j)
                for (int r = 0; r < 4; ++r) O[v][j][r] *= alO[r];
            for (int c = 0; c < 4; ++c)
                for (int j = 0; j < 4; ++j)
                    O[v][j] = MFMA16H(pa[c], vf[c][j], O[v][j]);
        }
    }

    const size_t slot = (size_t)h * 80 + idx;
    for (int v = 0; v < 2; ++v)
        for (int j = 0; j < 4; ++j)
            for (int r = 0; r < 4; ++r) {
                int row = w * 16 + quad * 4 + r;
                part_O[((slot * 2 + v) * 64 + row) * 64 + j * 16 + l16] = (__bf16)O[v][j][r];
            }
    if (quad == 0)
        for (int v = 0; v < 2; ++v)
            part_ml[(slot * 2 + v) * 64 + w * 16 + l16] = make_float2(m_[v], l_[v]);
    for (int off = 1; off < 64; off <<= 1) sigsum += __shfl_xor(sigsum, off);
    if (lane == 0) atomicAdd(sigacc, sigsum);
}

// ---------------- combine partials -> cat ----------------
__global__ __launch_bounds__(256) void attn_combine_kernel(
    const __bf16* __restrict__ part_O, const float2* __restrict__ part_ml,
    __bf16* __restrict__ cat)
{
    const int qt = blockIdx.x, h = blockIdx.y;
    const int nsp = (qt >> 3) + 1;
    const int base = (qt < 8) ? qt : (qt < 16) ? 8 + (qt - 8) * 2
                   : (qt < 24) ? 24 + (qt - 16) * 3 : 48 + (qt - 24) * 4;
    const int tid = threadIdx.x;
    const int row = tid >> 2, v = (tid >> 1) & 1, colh = (tid & 1) * 32;

    float2 ml[4];
    float M = -1e30f;
    for (int p = 0; p < nsp; ++p) {
        ml[p] = part_ml[(((size_t)h * 80 + base + p) * 2 + v) * 64 + row];
        M = fmaxf(M, ml[p].x);
    }
    float L = 0.f;
    float acc[32] = {};
    for (int p = 0; p < nsp; ++p) {
        float sc = __expf(ml[p].x - M);
        L += sc * ml[p].y;
        const __bf16* src =
            &part_O[((((size_t)h * 80 + base + p) * 2 + v) * 64 + row) * 64 + colh];
        for (int k = 0; k < 4; ++k) {
            bf16x8 o = *(const bf16x8*)&src[k * 8];
            for (int e = 0; e < 8; ++e) acc[k * 8 + e] += sc * (float)o[e];
        }
    }
    float inv = 1.f / L;
    __bf16* dst = &cat[(size_t)(qt * 64 + row) * 2048 + v * 1024 + h * 64 + colh];
    for (int k = 0; k < 4; ++k) {
        union { __bf16 hh[8]; float4 f4; } u;
        for (int e = 0; e < 8; ++e) u.hh[e] = (__bf16)(acc[k * 8 + e] * inv);
        *(float4*)&dst[k * 8] = u.f4;
    }
}

// ---------------- sigmoid-sum over strict upper tiles ----------------
__global__ void zero_acc_kernel(float* acc) { acc[0] = 0.f; }

__global__ __launch_bounds__(256) void sigmean_upper_kernel(
    const float* __restrict__ lm, float* __restrict__ acc)
{
    const int qt = blockIdx.x, h = blockIdx.y, rg = blockIdx.z;
    const int sc0 = (qt + 1) * 64;
    const int len4 = (T_SEQ - sc0) >> 2;
    float s = 0.f;
    for (int r = 0; r < 16; ++r) {
        const float* rowp = &lm[((size_t)h * T_SEQ + qt * 64 + rg * 16 + r) * T_SEQ + sc0];
        for (int c = threadIdx.x; c < len4; c += 256) {
            float4 a = *(const float4*)&rowp[c * 4];
            s += sigm(a.x) + sigm(a.y) + sigm(a.z) + sigm(a.w);
        }
    }
    for (int off = 1; off < 64; off <<= 1) s += __shfl_xor(s, off);
    if ((threadIdx.x & 63) == 0) atomicAdd(acc, s);
}

__global__ void write_sp_kernel(const float* __restrict__ acc, float* __restrict__ out)
{
    out[(size_t)T_SEQ * D_MODEL] = 0.0005f * acc[0] * (1.f / 67108864.f);
}

// ---------------- launch ----------------
extern "C" void kernel_launch(void* const* d_in, const int* in_sizes, int n_in,
                              void* d_out, int out_size, void* d_ws, size_t ws_size,
                              hipStream_t stream)
{
    const float* x      = (const float*)d_in[0];
    const float* W_qkv  = (const float*)d_in[2];
    const float* W_out  = (const float*)d_in[3];
    const float* lmask  = (const float*)d_in[4];
    const float* W_gate = (const float*)d_in[5];
    const float* b_gate = (const float*)d_in[6];
    const float* g1     = (const float*)d_in[7];
    const float* b1     = (const float*)d_in[8];
    const float* g2     = (const float*)d_in[9];
    const float* b2     = (const float*)d_in[10];
    const float* W_ff1  = (const float*)d_in[11];
    const float* b_ff1  = (const float*)d_in[12];
    const float* W_ff2  = (const float*)d_in[13];
    const float* b_ff2  = (const float*)d_in[14];
    float* out = (float*)d_out;

    char* ws = (char*)d_ws;
    size_t off = 0;
    auto alloc = [&](size_t bytes) {
        char* p = ws + off;
        off += (bytes + 255) & ~(size_t)255;
        return p;
    };
    __bf16* wq_b   = (__bf16*)alloc((size_t)3072 * 1024 * 2);
    __bf16* wout_b = (__bf16*)alloc((size_t)1024 * 1024 * 2);
    __bf16* wg_b   = (__bf16*)alloc((size_t)1024 * 2048 * 2);
    __bf16* wf1_b  = (__bf16*)alloc((size_t)4096 * 1024 * 2);
    __bf16* wf2_b  = (__bf16*)alloc((size_t)1024 * 4096 * 2);
    __bf16* xn_b   = (__bf16*)alloc((size_t)2048 * 1024 * 2);
    __bf16* qkv_b  = (__bf16*)alloc((size_t)2048 * 3072 * 2);
    _Float16* vt_h = (_Float16*)alloc((size_t)16 * 64 * 2048 * 2);
    __bf16* cat_b  = (__bf16*)alloc((size_t)2048 * 2048 * 2);
    __bf16* a1_b   = (__bf16*)alloc((size_t)2048 * 1024 * 2);
    float*  h_f    = (float*)alloc((size_t)2048 * 1024 * 4);
    __bf16* hn_b   = (__bf16*)alloc((size_t)2048 * 1024 * 2);
    __bf16* e_b    = (__bf16*)alloc((size_t)2048 * 4096 * 2);
    __bf16* part_O = (__bf16*)alloc((size_t)16 * 80 * 2 * 64 * 64 * 2);
    float2* part_ml= (float2*)alloc((size_t)16 * 80 * 2 * 64 * 8);
    float*  psum   = (float*)alloc((size_t)2 * 2048 * 1024 * 4);  // split-K partials
    float*  acc    = (float*)alloc(256);
    float*  psum1  = psum + (size_t)2048 * 1024;

    zero_acc_kernel<<<1, 1, 0, stream>>>(acc);

    cast_all_kernel<<<7168, 256, 0, stream>>>(W_qkv, W_out, W_gate, W_ff1, W_ff2,
                                              wq_b, wout_b, wg_b, wf1_b, wf2_b);

    ln_kernel<<<2048, 256, 0, stream>>>(x, g1, b1, xn_b);
    // qkv: BM=64 tiles -> grid 768 (3 blocks/CU)
    gemm_nt<64, 0><<<dim3(32, 24), 256, 0, stream>>>(xn_b, wq_b, nullptr, qkv_b, nullptr, 2048, 3072, 1024, 1024);
    vtrans_kernel<<<dim3(32, 16), 256, 0, stream>>>(qkv_b, vt_h);
    attn_split_kernel<<<dim3(80, 16), 256, 0, stream>>>(qkv_b, vt_h, lmask, part_O, part_ml, acc);
    attn_combine_kernel<<<dim3(32, 16), 256, 0, stream>>>(part_O, part_ml, cat_b);
    sigmean_upper_kernel<<<dim3(32, 16, 4), 256, 0, stream>>>(lmask, acc);

    // gate: split-K=2 (K=2048 -> 2x1024), grid 512
    gemm_nt<64, 3><<<dim3(32, 8, 2), 256, 0, stream>>>(cat_b, wg_b, nullptr, nullptr, psum, 2048, 1024, 1024, 2048);
    combine_kernel<0><<<2048, 256, 0, stream>>>(psum, psum1, b_gate, nullptr, a1_b, nullptr);
    // out: split-K=2 (K=1024 -> 2x512), grid 512
    gemm_nt<64, 3><<<dim3(32, 8, 2), 256, 0, stream>>>(a1_b, wout_b, nullptr, nullptr, psum, 2048, 1024, 512, 1024);
    combine_kernel<1><<<2048, 256, 0, stream>>>(psum, psum1, nullptr, x, nullptr, h_f);
    ln_kernel<<<2048, 256, 0, stream>>>(h_f, g2, b2, hn_b);
    // ff1: 128x128 tiles, grid 512 (2 blocks/CU)
    gemm_nt<128, 1><<<dim3(16, 32), 256, 0, stream>>>(hn_b, wf1_b, b_ff1, e_b, nullptr, 2048, 4096, 1024, 1024);
    // ff2: split-K=2 (K=4096 -> 2x2048), grid 512
    gemm_nt<64, 3><<<dim3(32, 8, 2), 256, 0, stream>>>(e_b, wf2_b, nullptr, nullptr, psum, 2048, 1024, 2048, 4096);
    combine_kernel<2><<<2048, 256, 0, stream>>>(psum, psum1, b_ff2, h_f, nullptr, out);

    write_sp_kernel<<<1, 1, 0, stream>>>(acc, out);

    (void)in_sizes; (void)n_in; (void)out_size; (void)ws_size;
}

// Round 7
// 667.608 us; speedup vs baseline: 1.2256x; 1.1722x over previous
//
#include <hip/hip_runtime.h>
#include <hip/hip_bf16.h>

typedef __bf16 bf16x8 __attribute__((ext_vector_type(8)));
typedef _Float16 f16x4 __attribute__((ext_vector_type(4)));
typedef float f32x4 __attribute__((ext_vector_type(4)));

#define MFMA16(a, b, c) __builtin_amdgcn_mfma_f32_16x16x32_bf16(a, b, c, 0, 0, 0)
#define MFMA16H(a, b, c) __builtin_amdgcn_mfma_f32_16x16x16f16(a, b, c, 0, 0, 0)

#define T_SEQ 2048
#define D_MODEL 1024
#define N_HEADS 16
#define HEAD_DIM 64
#define D_FF 4096
#define QKV_STRIDE 3072

__device__ __forceinline__ float sigm(float x) { return 1.f / (1.f + __expf(-x)); }

__device__ __forceinline__ void g2l16(const void* g, void* l)
{
    __builtin_amdgcn_global_load_lds(
        (const __attribute__((address_space(1))) void*)g,
        (__attribute__((address_space(3))) void*)l, 16, 0, 0);
}

__device__ __forceinline__ float bperm(int srclane, float v)
{
    return __builtin_bit_cast(float,
        __builtin_amdgcn_ds_bpermute(srclane * 4, __builtin_bit_cast(int, v)));
}

// ---------------- all weight casts fused + acc zero ----------------
#define N8_QKV 393216
#define N8_OUT 131072
#define N8_GATE 262144
#define N8_FF1 524288
#define N8_FF2 524288
__global__ __launch_bounds__(256) void cast_all_kernel(
    const float* __restrict__ s0, const float* __restrict__ s1,
    const float* __restrict__ s2, const float* __restrict__ s3,
    const float* __restrict__ s4,
    __bf16* __restrict__ d0, __bf16* __restrict__ d1, __bf16* __restrict__ d2,
    __bf16* __restrict__ d3, __bf16* __restrict__ d4, float* __restrict__ acc)
{
    int i = blockIdx.x * 256 + threadIdx.x;
    if (i == 0) acc[0] = 0.f;
    const float* s; __bf16* d; int j;
    if (i < N8_QKV)                           { s = s0; d = d0; j = i; }
    else if (i < N8_QKV + N8_OUT)             { s = s1; d = d1; j = i - N8_QKV; }
    else if (i < N8_QKV + N8_OUT + N8_GATE)   { s = s2; d = d2; j = i - N8_QKV - N8_OUT; }
    else if (i < N8_QKV + N8_OUT + N8_GATE + N8_FF1)
        { s = s3; d = d3; j = i - N8_QKV - N8_OUT - N8_GATE; }
    else { s = s4; d = d4; j = i - N8_QKV - N8_OUT - N8_GATE - N8_FF1; }
    const float4* p = (const float4*)s + (size_t)j * 2;
    float4 a = p[0], b = p[1];
    union { __bf16 h[8]; float4 v; } u;
    u.h[0] = (__bf16)a.x; u.h[1] = (__bf16)a.y; u.h[2] = (__bf16)a.z; u.h[3] = (__bf16)a.w;
    u.h[4] = (__bf16)b.x; u.h[5] = (__bf16)b.y; u.h[6] = (__bf16)b.z; u.h[7] = (__bf16)b.w;
    ((float4*)d)[j] = u.v;
}

// ---------------- LayerNorm (LN1): fp32 in -> bf16 out ----------------
__global__ __launch_bounds__(256) void ln_kernel(
    const float* __restrict__ x, const float* __restrict__ g,
    const float* __restrict__ b, __bf16* __restrict__ out)
{
    const int t = blockIdx.x;
    const int tid = threadIdx.x;
    float4 xv = *(const float4*)&x[t * D_MODEL + tid * 4];
    float s = xv.x + xv.y + xv.z + xv.w;
    float ss = xv.x * xv.x + xv.y * xv.y + xv.z * xv.z + xv.w * xv.w;
    for (int off = 1; off < 64; off <<= 1) {
        s += __shfl_xor(s, off);
        ss += __shfl_xor(ss, off);
    }
    __shared__ float sb[8];
    int w = tid >> 6, lane = tid & 63;
    if (lane == 0) { sb[w] = s; sb[4 + w] = ss; }
    __syncthreads();
    s = sb[0] + sb[1] + sb[2] + sb[3];
    ss = sb[4] + sb[5] + sb[6] + sb[7];
    float mu = s * (1.f / D_MODEL);
    float var = ss * (1.f / D_MODEL) - mu * mu;
    float rs = rsqrtf(var + 1e-5f);
    const float* xp = (const float*)&xv;
    for (int i = 0; i < 4; ++i) {
        int d = tid * 4 + i;
        out[t * D_MODEL + d] = (__bf16)((xp[i] - mu) * rs * g[d] + b[d]);
    }
}

// ---------------- NT GEMM, BK=64, split-K via blockIdx.z ----------
// EPI 1: bias + exact GELU -> bf16; EPI 3: fp32 partial (slice z);
// EPI 4: qkv fused -- bn<2048 normal bf16 store, bn>=2048 transposed f16 -> vt.
template<int BM, int EPI>
__global__ __launch_bounds__(256) void gemm_nt(
    const __bf16* __restrict__ A, const __bf16* __restrict__ B,
    const float* __restrict__ bias,
    __bf16* __restrict__ outb, float* __restrict__ outf, _Float16* __restrict__ vtout,
    int M, int N, int klen, int lda)
{
    constexpr int BN = 128;
    constexpr int STAGE = (BM + BN) * 64 * 2;
    constexpr int CTB = (EPI == 3) ? BM * BN * 4 : (EPI == 4) ? BM * 132 * 4 : BM * BN * 2;
    constexpr int SMEM = (STAGE > CTB) ? STAGE : CTB;
    __shared__ __align__(16) char smem[SMEM];
    __bf16* As = (__bf16*)smem;
    __bf16* Bs = As + BM * 64;

    const int tid = threadIdx.x;
    const int lane = tid & 63, w = tid >> 6;
    const int quad = lane >> 4, l16 = lane & 15;
    const int bm = blockIdx.x * BM, bn = blockIdx.y * BN;
    const int koff = blockIdx.z * klen;
    if (EPI == 3) outf += (size_t)blockIdx.z * M * N;
    constexpr int NI = 4;
    constexpr int NJ = (BM == 128) ? 4 : 2;
    const int wm = (BM == 128) ? (w & 1) * 64 : 0;
    const int wn = (BM == 128) ? (w >> 1) * 64 : w * 32;

    f32x4 acc[NI][NJ] = {};

    for (int k0 = 0; k0 < klen; k0 += 64) {
        __syncthreads();
        constexpr int AIT = BM * 8 / 256;
        for (int it = 0; it < AIT; ++it) {
            int c = it * 256 + tid;
            int tile = (c >= BM * 4) ? 1 : 0;
            int c2 = c & (BM * 4 - 1);
            g2l16(&A[(size_t)(bm + (c2 >> 2)) * lda + koff + k0 + tile * 32 + ((c2 & 3) << 3)],
                  &As[c * 8]);
        }
        for (int it = 0; it < 4; ++it) {
            int c = it * 256 + tid;
            int tile = (c >= 512) ? 1 : 0;
            int c2 = c & 511;
            g2l16(&B[(size_t)(bn + (c2 >> 2)) * lda + koff + k0 + tile * 32 + ((c2 & 3) << 3)],
                  &Bs[c * 8]);
        }
        __syncthreads();
        for (int ks = 0; ks < 2; ++ks) {
            bf16x8 af[NI], bfr[NJ];
            for (int i = 0; i < NI; ++i)
                af[i] = *(const bf16x8*)&As[ks * BM * 32 + (wm + i * 16 + l16) * 32 + quad * 8];
            for (int j = 0; j < NJ; ++j)
                bfr[j] = *(const bf16x8*)&Bs[ks * BN * 32 + (wn + j * 16 + l16) * 32 + quad * 8];
            for (int i = 0; i < NI; ++i)
                for (int j = 0; j < NJ; ++j)
                    acc[i][j] = MFMA16(af[i], bfr[j], acc[i][j]);
        }
    }

    __syncthreads();
    if (EPI == 3) {
        float* Ct = (float*)smem;
        for (int i = 0; i < NI; ++i)
            for (int j = 0; j < NJ; ++j)
                for (int r = 0; r < 4; ++r)
                    Ct[(wm + i * 16 + quad * 4 + r) * BN + wn + j * 16 + l16] = acc[i][j][r];
        __syncthreads();
        constexpr int IT = BM * BN / 4 / 256;
        for (int it = 0; it < IT; ++it) {
            int c = it * 256 + tid;
            int row = c >> 5, col = (c & 31) << 2;
            *(float4*)&outf[(size_t)(bm + row) * N + bn + col] = *(float4*)&Ct[row * BN + col];
        }
    } else if (EPI == 4) {
        float* Ct = (float*)smem;                   // [BM][132] padded fp32
        for (int i = 0; i < NI; ++i)
            for (int j = 0; j < NJ; ++j)
                for (int r = 0; r < 4; ++r)
                    Ct[(wm + i * 16 + quad * 4 + r) * 132 + wn + j * 16 + l16] = acc[i][j][r];
        __syncthreads();
        if (bn < 2048) {
            for (int it = 0; it < BM * BN / 8 / 256; ++it) {
                int c = it * 256 + tid;
                int row = c >> 4, col8 = (c & 15) << 3;
                float4 f0 = *(float4*)&Ct[row * 132 + col8];
                float4 f1 = *(float4*)&Ct[row * 132 + col8 + 4];
                union { __bf16 h[8]; float4 v; } u;
                u.h[0] = (__bf16)f0.x; u.h[1] = (__bf16)f0.y; u.h[2] = (__bf16)f0.z; u.h[3] = (__bf16)f0.w;
                u.h[4] = (__bf16)f1.x; u.h[5] = (__bf16)f1.y; u.h[6] = (__bf16)f1.z; u.h[7] = (__bf16)f1.w;
                *(float4*)&outb[(size_t)(bm + row) * N + bn + col8] = u.v;
            }
        } else {
            // transposed store to vt[h*64+dh][t]
            int col = tid & 127;
            int r0 = (tid >> 7) * 32;
            int gcol = bn - 2048 + col;
            _Float16 buf[32];
            for (int r = 0; r < 32; ++r)
                buf[r] = (_Float16)Ct[(r0 + r) * 132 + col];
            _Float16* dst = &vtout[(size_t)gcol * T_SEQ + bm + r0];
            for (int k = 0; k < 4; ++k)
                *(float4*)&dst[k * 8] = *(float4*)&buf[k * 8];
        }
    } else {
        __bf16* Ct = (__bf16*)smem;
        for (int i = 0; i < NI; ++i)
            for (int j = 0; j < NJ; ++j)
                for (int r = 0; r < 4; ++r) {
                    int row = wm + i * 16 + quad * 4 + r;
                    int col = wn + j * 16 + l16;
                    float v = acc[i][j][r];
                    if (bias) v += bias[bn + col];
                    if (EPI == 1) v = 0.5f * v * (1.f + erff(v * 0.70710678118f));
                    Ct[row * BN + col] = (__bf16)v;
                }
        __syncthreads();
        constexpr int IT = BM * BN / 8 / 256;
        for (int it = 0; it < IT; ++it) {
            int c = it * 256 + tid;
            int row = c >> 4, col = (c & 15) << 3;
            *(float4*)&outb[(size_t)(bm + row) * N + bn + col] = *(float4*)&Ct[row * BN + col];
        }
    }
}

// ---------------- split-K combine. MODE 0: bf16(p0+p1+bias) ----------------
// MODE 2: fp32 p0+p1+bias+resid (+sp scalar write)
template<int MODE>
__global__ __launch_bounds__(256) void combine_kernel(
    const float* __restrict__ p0, const float* __restrict__ p1,
    const float* __restrict__ bias, const float* __restrict__ resid,
    __bf16* __restrict__ outb, float* __restrict__ outf,
    const float* __restrict__ sigacc)
{
    int i = blockIdx.x * 256 + threadIdx.x;
    float4 a = ((const float4*)p0)[i];
    float4 b = ((const float4*)p1)[i];
    int col = (i & 255) << 2;
    float4 bb = *(const float4*)&bias[col];
    float v[4] = {a.x + b.x + bb.x, a.y + b.y + bb.y, a.z + b.z + bb.z, a.w + b.w + bb.w};
    if (MODE == 2) {
        float4 r = ((const float4*)resid)[i];
        v[0] += r.x; v[1] += r.y; v[2] += r.z; v[3] += r.w;
        float4 o = {v[0], v[1], v[2], v[3]};
        ((float4*)outf)[i] = o;
        if (i == 0)
            outf[(size_t)T_SEQ * D_MODEL] = 0.0005f * sigacc[0] * (1.f / 67108864.f);
    } else {
        union { __bf16 h[4]; float2 f2; } u;
        for (int e = 0; e < 4; ++e) u.h[e] = (__bf16)v[e];
        ((float2*)outb)[i] = u.f2;
    }
}

// ---------------- split-K combine + residual + LN2 fused ----------------
// block = one row: h = p0+p1+resid -> h_out; LN(h) -> hn_out (bf16)
__global__ __launch_bounds__(256) void combine_ln_kernel(
    const float* __restrict__ p0, const float* __restrict__ p1,
    const float* __restrict__ resid, const float* __restrict__ g,
    const float* __restrict__ b, float* __restrict__ h_out,
    __bf16* __restrict__ hn_out)
{
    const int t = blockIdx.x, tid = threadIdx.x;
    const int i = t * 256 + tid;
    float4 a = ((const float4*)p0)[i];
    float4 bb = ((const float4*)p1)[i];
    float4 r = ((const float4*)resid)[i];
    float4 v = {a.x + bb.x + r.x, a.y + bb.y + r.y, a.z + bb.z + r.z, a.w + bb.w + r.w};
    ((float4*)h_out)[i] = v;
    float s = v.x + v.y + v.z + v.w;
    float ss = v.x * v.x + v.y * v.y + v.z * v.z + v.w * v.w;
    for (int off = 1; off < 64; off <<= 1) {
        s += __shfl_xor(s, off);
        ss += __shfl_xor(ss, off);
    }
    __shared__ float sb[8];
    int w = tid >> 6, lane = tid & 63;
    if (lane == 0) { sb[w] = s; sb[4 + w] = ss; }
    __syncthreads();
    s = sb[0] + sb[1] + sb[2] + sb[3];
    ss = sb[4] + sb[5] + sb[6] + sb[7];
    float mu = s * (1.f / D_MODEL);
    float var = ss * (1.f / D_MODEL) - mu * mu;
    float rs = rsqrtf(var + 1e-5f);
    const float* vp = (const float*)&v;
    union { __bf16 h[4]; float2 f2; } u;
    for (int k = 0; k < 4; ++k) {
        int d = tid * 4 + k;
        u.h[k] = (__bf16)((vp[k] - mu) * rs * g[d] + b[d]);
    }
    ((float2*)hn_out)[i] = u.f2;
}

// ---------------- split-s dual-variant flash attention ----------------
// Double-buffered K/V staging, ONE barrier per chunk, g2l16 prefetch.
// Fused: sigmoid-sum of lower tiles (incl. diag) AND of transpose (upper) tiles.
__global__ __launch_bounds__(256) void attn_split_kernel(
    const __bf16* __restrict__ qkv, const _Float16* __restrict__ vt,
    const float* __restrict__ lmask,
    __bf16* __restrict__ part_O, float2* __restrict__ part_ml,
    float* __restrict__ sigacc)
{
    __shared__ __bf16 KsAll[2 * 4096];   // 2 bufs x (two [64][32] half-tiles)
    __shared__ _Float16 VsAll[2 * 4096]; // 2 bufs x [64 dh][64 s] swizzled

    const int tid = threadIdx.x;
    const int w = tid >> 6, lane = tid & 63;
    const int quad = lane >> 4, l16 = lane & 15;
    const int idx = blockIdx.x, h = blockIdx.y;
    int qt, sp;
    if (idx < 8)       { qt = idx;                sp = 0; }
    else if (idx < 24) { qt = 8 + ((idx - 8) >> 1);  sp = (idx - 8) & 1; }
    else if (idx < 48) { qt = 16 + (idx - 24) / 3;   sp = (idx - 24) % 3; }
    else               { qt = 24 + ((idx - 48) >> 2); sp = (idx - 48) & 3; }
    const int q0 = qt * 64;
    const int sbeg = sp * 512;
    const int send = min(sbeg + 512, q0 + 64);
    const int nch = (send - sbeg) >> 6;

    auto stage = [&](int s0, int bsel) {
        __bf16* kd = &KsAll[bsel * 4096];
        _Float16* vd = &VsAll[bsel * 4096];
        for (int it = 0; it < 2; ++it) {
            int c = it * 256 + tid;
            int tile = c >> 8, c2 = c & 255;
            g2l16(&qkv[(size_t)(s0 + (c2 >> 2)) * QKV_STRIDE + 1024 + h * 64 + tile * 32 + ((c2 & 3) << 3)],
                  &kd[c * 8]);
        }
        for (int it = 0; it < 2; ++it) {
            int c = it * 256 + tid;
            int dh = c >> 3, g = c & 7;
            int sIn = ((g + dh) & 7) * 8;
            g2l16(&vt[((size_t)h * 64 + dh) * T_SEQ + s0 + sIn], &vd[c * 8]);
        }
    };

    const int tq = q0 + w * 16 + l16;
    bf16x8 qf0 = *(const bf16x8*)&qkv[(size_t)tq * QKV_STRIDE + h * 64 + quad * 8];
    bf16x8 qf1 = *(const bf16x8*)&qkv[(size_t)tq * QKV_STRIDE + h * 64 + 32 + quad * 8];

    float m_[2] = {-1e30f, -1e30f}, l_[2] = {0.f, 0.f};
    f32x4 O[2][4] = {};
    float sigsum = 0.f;

    stage(sbeg, 0);

    for (int ci = 0; ci < nch; ++ci) {
        const int s0 = sbeg + (ci << 6);
        const int cur = ci & 1;
        __syncthreads();   // drains stage(ci) issued one chunk ago (or prologue)

        // lmask loads for this chunk (issued BEFORE the prefetch so their
        // vmcnt wait does not drain the prefetch)
        float4 lm[4];
        for (int c = 0; c < 4; ++c)
            lm[c] = *(const float4*)&lmask[((size_t)h * T_SEQ + tq) * T_SEQ + s0 + c * 16 + quad * 4];
        float4 up[4];
        const bool lower = (s0 + 64 <= q0);
        if (lower) {
            const float* upp = &lmask[((size_t)h * T_SEQ + s0 + (tid >> 2)) * T_SEQ + q0 + ((tid & 3) << 4)];
            for (int k = 0; k < 4; ++k) up[k] = *(const float4*)&upp[k * 4];
        }

        if (ci + 1 < nch) stage(s0 + 64, cur ^ 1);   // async prefetch

        const __bf16* Ks = &KsAll[cur * 4096];
        const _Float16* Vs = &VsAll[cur * 4096];

        f32x4 St[4];
        for (int c = 0; c < 4; ++c) {
            bf16x8 kf0 = *(const bf16x8*)&Ks[(c * 16 + l16) * 32 + quad * 8];
            bf16x8 kf1 = *(const bf16x8*)&Ks[2048 + (c * 16 + l16) * 32 + quad * 8];
            f32x4 z = {};
            z = MFMA16(kf0, qf0, z);
            z = MFMA16(kf1, qf1, z);
            St[c] = z * 0.125f;
        }
        f16x4 vf[4][4];
        for (int c = 0; c < 4; ++c)
            for (int j = 0; j < 4; ++j) {
                int dh = j * 16 + l16;
                int gg = ((2 * c + (quad >> 1)) - dh) & 7;
                vf[c][j] = *(const f16x4*)&Vs[dh * 64 + gg * 8 + (quad & 1) * 4];
            }

        if (lower)
            for (int k = 0; k < 4; ++k) {
                const float* uu = (const float*)&up[k];
                sigsum += sigm(uu[0]) + sigm(uu[1]) + sigm(uu[2]) + sigm(uu[3]);
            }
        float sg[4][4];
        for (int c = 0; c < 4; ++c) {
            const float* lp = (const float*)&lm[c];
            for (int r = 0; r < 4; ++r) { sg[c][r] = sigm(lp[r]); sigsum += sg[c][r]; }
        }

        for (int v = 0; v < 2; ++v) {
            float p[4][4];
            float mx = -1e30f;
            for (int c = 0; c < 4; ++c) {
                int sbase = s0 + c * 16 + quad * 4;
                for (int r = 0; r < 4; ++r) {
                    float val = v ? St[c][r] * sg[c][r] : St[c][r];
                    val = (sbase + r > tq) ? -1e30f : val;
                    p[c][r] = val;
                    mx = fmaxf(mx, val);
                }
            }
            mx = fmaxf(mx, __shfl_xor(mx, 16));
            mx = fmaxf(mx, __shfl_xor(mx, 32));
            float mn = fmaxf(m_[v], mx);
            float al = __expf(m_[v] - mn);
            m_[v] = mn;
            float rs = 0.f;
            f16x4 pa[4];
            for (int c = 0; c < 4; ++c)
                for (int r = 0; r < 4; ++r) {
                    float e = __expf(p[c][r] - mn);
                    rs += e;
                    pa[c][r] = (_Float16)e;
                }
            rs += __shfl_xor(rs, 16);
            rs += __shfl_xor(rs, 32);
            l_[v] = l_[v] * al + rs;
            float alO[4];
            for (int r = 0; r < 4; ++r) alO[r] = bperm(quad * 4 + r, al);
            for (int j = 0; j < 4; ++j)
                for (int r = 0; r < 4; ++r) O[v][j][r] *= alO[r];
            for (int c = 0; c < 4; ++c)
                for (int j = 0; j < 4; ++j)
                    O[v][j] = MFMA16H(pa[c], vf[c][j], O[v][j]);
        }
    }

    const size_t slot = (size_t)h * 80 + idx;
    for (int v = 0; v < 2; ++v)
        for (int j = 0; j < 4; ++j)
            for (int r = 0; r < 4; ++r) {
                int row = w * 16 + quad * 4 + r;
                part_O[((slot * 2 + v) * 64 + row) * 64 + j * 16 + l16] = (__bf16)O[v][j][r];
            }
    if (quad == 0)
        for (int v = 0; v < 2; ++v)
            part_ml[(slot * 2 + v) * 64 + w * 16 + l16] = make_float2(m_[v], l_[v]);
    for (int off = 1; off < 64; off <<= 1) sigsum += __shfl_xor(sigsum, off);
    if (lane == 0) atomicAdd(sigacc, sigsum);
}

// ---------------- combine partials -> cat ----------------
__global__ __launch_bounds__(256) void attn_combine_kernel(
    const __bf16* __restrict__ part_O, const float2* __restrict__ part_ml,
    __bf16* __restrict__ cat)
{
    const int qt = blockIdx.x, h = blockIdx.y;
    const int nsp = (qt >> 3) + 1;
    const int base = (qt < 8) ? qt : (qt < 16) ? 8 + (qt - 8) * 2
                   : (qt < 24) ? 24 + (qt - 16) * 3 : 48 + (qt - 24) * 4;
    const int tid = threadIdx.x;
    const int row = tid >> 2, v = (tid >> 1) & 1, colh = (tid & 1) * 32;

    float2 ml[4];
    float M = -1e30f;
    for (int p = 0; p < nsp; ++p) {
        ml[p] = part_ml[(((size_t)h * 80 + base + p) * 2 + v) * 64 + row];
        M = fmaxf(M, ml[p].x);
    }
    float L = 0.f;
    float acc[32] = {};
    for (int p = 0; p < nsp; ++p) {
        float sc = __expf(ml[p].x - M);
        L += sc * ml[p].y;
        const __bf16* src =
            &part_O[((((size_t)h * 80 + base + p) * 2 + v) * 64 + row) * 64 + colh];
        for (int k = 0; k < 4; ++k) {
            bf16x8 o = *(const bf16x8*)&src[k * 8];
            for (int e = 0; e < 8; ++e) acc[k * 8 + e] += sc * (float)o[e];
        }
    }
    float inv = 1.f / L;
    __bf16* dst = &cat[(size_t)(qt * 64 + row) * 2048 + v * 1024 + h * 64 + colh];
    for (int k = 0; k < 4; ++k) {
        union { __bf16 hh[8]; float4 f4; } u;
        for (int e = 0; e < 8; ++e) u.hh[e] = (__bf16)(acc[k * 8 + e] * inv);
        *(float4*)&dst[k * 8] = u.f4;
    }
}

// ---------------- launch ----------------
extern "C" void kernel_launch(void* const* d_in, const int* in_sizes, int n_in,
                              void* d_out, int out_size, void* d_ws, size_t ws_size,
                              hipStream_t stream)
{
    const float* x      = (const float*)d_in[0];
    const float* W_qkv  = (const float*)d_in[2];
    const float* W_out  = (const float*)d_in[3];
    const float* lmask  = (const float*)d_in[4];
    const float* W_gate = (const float*)d_in[5];
    const float* b_gate = (const float*)d_in[6];
    const float* g1     = (const float*)d_in[7];
    const float* b1     = (const float*)d_in[8];
    const float* g2     = (const float*)d_in[9];
    const float* b2     = (const float*)d_in[10];
    const float* W_ff1  = (const float*)d_in[11];
    const float* b_ff1  = (const float*)d_in[12];
    const float* W_ff2  = (const float*)d_in[13];
    const float* b_ff2  = (const float*)d_in[14];
    float* out = (float*)d_out;

    char* ws = (char*)d_ws;
    size_t off = 0;
    auto alloc = [&](size_t bytes) {
        char* p = ws + off;
        off += (bytes + 255) & ~(size_t)255;
        return p;
    };
    __bf16* wq_b   = (__bf16*)alloc((size_t)3072 * 1024 * 2);
    __bf16* wout_b = (__bf16*)alloc((size_t)1024 * 1024 * 2);
    __bf16* wg_b   = (__bf16*)alloc((size_t)1024 * 2048 * 2);
    __bf16* wf1_b  = (__bf16*)alloc((size_t)4096 * 1024 * 2);
    __bf16* wf2_b  = (__bf16*)alloc((size_t)1024 * 4096 * 2);
    __bf16* xn_b   = (__bf16*)alloc((size_t)2048 * 1024 * 2);
    __bf16* qkv_b  = (__bf16*)alloc((size_t)2048 * 3072 * 2);
    _Float16* vt_h = (_Float16*)alloc((size_t)16 * 64 * 2048 * 2);
    __bf16* cat_b  = (__bf16*)alloc((size_t)2048 * 2048 * 2);
    __bf16* a1_b   = (__bf16*)alloc((size_t)2048 * 1024 * 2);
    float*  h_f    = (float*)alloc((size_t)2048 * 1024 * 4);
    __bf16* hn_b   = (__bf16*)alloc((size_t)2048 * 1024 * 2);
    __bf16* e_b    = (__bf16*)alloc((size_t)2048 * 4096 * 2);
    __bf16* part_O = (__bf16*)alloc((size_t)16 * 80 * 2 * 64 * 64 * 2);
    float2* part_ml= (float2*)alloc((size_t)16 * 80 * 2 * 64 * 8);
    float*  psum   = (float*)alloc((size_t)2 * 2048 * 1024 * 4);
    float*  acc    = (float*)alloc(256);
    float*  psum1  = psum + (size_t)2048 * 1024;

    // 1. weight casts (+ acc zero)
    cast_all_kernel<<<7168, 256, 0, stream>>>(W_qkv, W_out, W_gate, W_ff1, W_ff2,
                                              wq_b, wout_b, wg_b, wf1_b, wf2_b, acc);
    // 2. LN1
    ln_kernel<<<2048, 256, 0, stream>>>(x, g1, b1, xn_b);
    // 3. qkv GEMM (fused V transpose into vt)
    gemm_nt<64, 4><<<dim3(32, 24), 256, 0, stream>>>(xn_b, wq_b, nullptr, qkv_b, nullptr, vt_h, 2048, 3072, 1024, 1024);
    // 4. attention (fused full sigmoid-sum of lmask)
    attn_split_kernel<<<dim3(80, 16), 256, 0, stream>>>(qkv_b, vt_h, lmask, part_O, part_ml, acc);
    // 5. attention combine -> cat
    attn_combine_kernel<<<dim3(32, 16), 256, 0, stream>>>(part_O, part_ml, cat_b);
    // 6-7. gate (split-K=2) + combine
    gemm_nt<64, 3><<<dim3(32, 8, 2), 256, 0, stream>>>(cat_b, wg_b, nullptr, nullptr, psum, nullptr, 2048, 1024, 1024, 2048);
    combine_kernel<0><<<2048, 256, 0, stream>>>(psum, psum1, b_gate, nullptr, a1_b, nullptr, nullptr);
    // 8-9. out-proj (split-K=2) + combine+resid+LN2
    gemm_nt<64, 3><<<dim3(32, 8, 2), 256, 0, stream>>>(a1_b, wout_b, nullptr, nullptr, psum, nullptr, 2048, 1024, 512, 1024);
    combine_ln_kernel<<<2048, 256, 0, stream>>>(psum, psum1, x, g2, b2, h_f, hn_b);
    // 10. ff1 + GELU
    gemm_nt<128, 1><<<dim3(16, 32), 256, 0, stream>>>(hn_b, wf1_b, b_ff1, e_b, nullptr, nullptr, 2048, 4096, 1024, 1024);
    // 11-12. ff2 (split-K=2) + combine+bias+resid (+sp write)
    gemm_nt<64, 3><<<dim3(32, 8, 2), 256, 0, stream>>>(e_b, wf2_b, nullptr, nullptr, psum, nullptr, 2048, 1024, 2048, 4096);
    combine_kernel<2><<<2048, 256, 0, stream>>>(psum, psum1, b_ff2, h_f, nullptr, out, acc);

    (void)in_sizes; (void)n_in; (void)out_size; (void)ws_size;
}

// Round 8
// 656.330 us; speedup vs baseline: 1.2467x; 1.0172x over previous
//
#include <hip/hip_runtime.h>
#include <hip/hip_bf16.h>

typedef __bf16 bf16x8 __attribute__((ext_vector_type(8)));
typedef _Float16 f16x4 __attribute__((ext_vector_type(4)));
typedef float f32x4 __attribute__((ext_vector_type(4)));

#define MFMA16(a, b, c) __builtin_amdgcn_mfma_f32_16x16x32_bf16(a, b, c, 0, 0, 0)
#define MFMA16H(a, b, c) __builtin_amdgcn_mfma_f32_16x16x16f16(a, b, c, 0, 0, 0)

#define T_SEQ 2048
#define D_MODEL 1024
#define N_HEADS 16
#define HEAD_DIM 64
#define D_FF 4096
#define QKV_STRIDE 3072

__device__ __forceinline__ float sigm(float x) { return 1.f / (1.f + __expf(-x)); }

__device__ __forceinline__ void g2l16(const void* g, void* l)
{
    __builtin_amdgcn_global_load_lds(
        (const __attribute__((address_space(1))) void*)g,
        (__attribute__((address_space(3))) void*)l, 16, 0, 0);
}

__device__ __forceinline__ float bperm(int srclane, float v)
{
    return __builtin_bit_cast(float,
        __builtin_amdgcn_ds_bpermute(srclane * 4, __builtin_bit_cast(int, v)));
}

// ---------------- all weight casts fused + acc zero ----------------
#define N8_QKV 393216
#define N8_OUT 131072
#define N8_GATE 262144
#define N8_FF1 524288
#define N8_FF2 524288
__global__ __launch_bounds__(256) void cast_all_kernel(
    const float* __restrict__ s0, const float* __restrict__ s1,
    const float* __restrict__ s2, const float* __restrict__ s3,
    const float* __restrict__ s4,
    __bf16* __restrict__ d0, __bf16* __restrict__ d1, __bf16* __restrict__ d2,
    __bf16* __restrict__ d3, __bf16* __restrict__ d4, float* __restrict__ acc)
{
    int i = blockIdx.x * 256 + threadIdx.x;
    if (i == 0) acc[0] = 0.f;
    const float* s; __bf16* d; int j;
    if (i < N8_QKV)                           { s = s0; d = d0; j = i; }
    else if (i < N8_QKV + N8_OUT)             { s = s1; d = d1; j = i - N8_QKV; }
    else if (i < N8_QKV + N8_OUT + N8_GATE)   { s = s2; d = d2; j = i - N8_QKV - N8_OUT; }
    else if (i < N8_QKV + N8_OUT + N8_GATE + N8_FF1)
        { s = s3; d = d3; j = i - N8_QKV - N8_OUT - N8_GATE; }
    else { s = s4; d = d4; j = i - N8_QKV - N8_OUT - N8_GATE - N8_FF1; }
    const float4* p = (const float4*)s + (size_t)j * 2;
    float4 a = p[0], b = p[1];
    union { __bf16 h[8]; float4 v; } u;
    u.h[0] = (__bf16)a.x; u.h[1] = (__bf16)a.y; u.h[2] = (__bf16)a.z; u.h[3] = (__bf16)a.w;
    u.h[4] = (__bf16)b.x; u.h[5] = (__bf16)b.y; u.h[6] = (__bf16)b.z; u.h[7] = (__bf16)b.w;
    ((float4*)d)[j] = u.v;
}

// ---------------- LayerNorm (LN1): fp32 in -> bf16 out ----------------
__global__ __launch_bounds__(256) void ln_kernel(
    const float* __restrict__ x, const float* __restrict__ g,
    const float* __restrict__ b, __bf16* __restrict__ out)
{
    const int t = blockIdx.x;
    const int tid = threadIdx.x;
    float4 xv = *(const float4*)&x[t * D_MODEL + tid * 4];
    float s = xv.x + xv.y + xv.z + xv.w;
    float ss = xv.x * xv.x + xv.y * xv.y + xv.z * xv.z + xv.w * xv.w;
    for (int off = 1; off < 64; off <<= 1) {
        s += __shfl_xor(s, off);
        ss += __shfl_xor(ss, off);
    }
    __shared__ float sb[8];
    int w = tid >> 6, lane = tid & 63;
    if (lane == 0) { sb[w] = s; sb[4 + w] = ss; }
    __syncthreads();
    s = sb[0] + sb[1] + sb[2] + sb[3];
    ss = sb[4] + sb[5] + sb[6] + sb[7];
    float mu = s * (1.f / D_MODEL);
    float var = ss * (1.f / D_MODEL) - mu * mu;
    float rs = rsqrtf(var + 1e-5f);
    const float* xp = (const float*)&xv;
    for (int i = 0; i < 4; ++i) {
        int d = tid * 4 + i;
        out[t * D_MODEL + d] = (__bf16)((xp[i] - mu) * rs * g[d] + b[d]);
    }
}

// ---------------- NT GEMM, BK=64, single-barrier LDS double-buffer ---------
// EPI 1: bias + exact GELU -> bf16; EPI 3: fp32 partial (split-K slice z);
// EPI 4: qkv fused -- bn<2048 normal bf16 store, bn>=2048 transposed f16 -> vt.
template<int BM, int EPI>
__global__ __launch_bounds__(256) void gemm_nt(
    const __bf16* __restrict__ A, const __bf16* __restrict__ B,
    const float* __restrict__ bias,
    __bf16* __restrict__ outb, float* __restrict__ outf, _Float16* __restrict__ vtout,
    int M, int N, int klen, int lda)
{
    constexpr int BN = 128;
    constexpr int SBUF = (BM + BN) * 64 * 2;     // bytes per staging buffer
    constexpr int STAGE = SBUF * 2;              // double-buffered
    constexpr int CTB = (EPI == 3) ? BM * BN * 4 : (EPI == 4) ? BM * 132 * 4 : BM * BN * 2;
    constexpr int SMEM = (STAGE > CTB) ? STAGE : CTB;
    __shared__ __align__(16) char smem[SMEM];

    const int tid = threadIdx.x;
    const int lane = tid & 63, w = tid >> 6;
    const int quad = lane >> 4, l16 = lane & 15;
    const int bm = blockIdx.x * BM, bn = blockIdx.y * BN;
    const int koff = blockIdx.z * klen;
    if (EPI == 3) outf += (size_t)blockIdx.z * M * N;
    constexpr int NI = 4;
    constexpr int NJ = (BM == 128) ? 4 : 2;
    const int wm = (BM == 128) ? (w & 1) * 64 : 0;
    const int wn = (BM == 128) ? (w >> 1) * 64 : w * 32;

    auto stageg = [&](int k0, int b) {
        __bf16* As = (__bf16*)(smem + b * SBUF);
        __bf16* Bs = As + BM * 64;
        constexpr int AIT = BM * 8 / 256;
        for (int it = 0; it < AIT; ++it) {
            int c = it * 256 + tid;
            int tile = (c >= BM * 4) ? 1 : 0;
            int c2 = c & (BM * 4 - 1);
            g2l16(&A[(size_t)(bm + (c2 >> 2)) * lda + koff + k0 + tile * 32 + ((c2 & 3) << 3)],
                  &As[c * 8]);
        }
        for (int it = 0; it < 4; ++it) {
            int c = it * 256 + tid;
            int tile = (c >= 512) ? 1 : 0;
            int c2 = c & 511;
            g2l16(&B[(size_t)(bn + (c2 >> 2)) * lda + koff + k0 + tile * 32 + ((c2 & 3) << 3)],
                  &Bs[c * 8]);
        }
    };

    f32x4 acc[NI][NJ] = {};
    const int nkt = klen >> 6;
    stageg(0, 0);

    for (int kt = 0; kt < nkt; ++kt) {
        __syncthreads();                         // drains stage(kt)
        if (kt + 1 < nkt) stageg((kt + 1) << 6, (kt + 1) & 1);   // async prefetch
        const __bf16* As = (const __bf16*)(smem + (kt & 1) * SBUF);
        const __bf16* Bs = As + BM * 64;
        for (int ks = 0; ks < 2; ++ks) {
            bf16x8 af[NI], bfr[NJ];
            for (int i = 0; i < NI; ++i)
                af[i] = *(const bf16x8*)&As[ks * BM * 32 + (wm + i * 16 + l16) * 32 + quad * 8];
            for (int j = 0; j < NJ; ++j)
                bfr[j] = *(const bf16x8*)&Bs[ks * BN * 32 + (wn + j * 16 + l16) * 32 + quad * 8];
            for (int i = 0; i < NI; ++i)
                for (int j = 0; j < NJ; ++j)
                    acc[i][j] = MFMA16(af[i], bfr[j], acc[i][j]);
        }
    }

    __syncthreads();
    if (EPI == 3) {
        float* Ct = (float*)smem;
        for (int i = 0; i < NI; ++i)
            for (int j = 0; j < NJ; ++j)
                for (int r = 0; r < 4; ++r)
                    Ct[(wm + i * 16 + quad * 4 + r) * BN + wn + j * 16 + l16] = acc[i][j][r];
        __syncthreads();
        constexpr int IT = BM * BN / 4 / 256;
        for (int it = 0; it < IT; ++it) {
            int c = it * 256 + tid;
            int row = c >> 5, col = (c & 31) << 2;
            *(float4*)&outf[(size_t)(bm + row) * N + bn + col] = *(float4*)&Ct[row * BN + col];
        }
    } else if (EPI == 4) {
        float* Ct = (float*)smem;                   // [BM][132] padded fp32
        for (int i = 0; i < NI; ++i)
            for (int j = 0; j < NJ; ++j)
                for (int r = 0; r < 4; ++r)
                    Ct[(wm + i * 16 + quad * 4 + r) * 132 + wn + j * 16 + l16] = acc[i][j][r];
        __syncthreads();
        if (bn < 2048) {
            for (int it = 0; it < BM * BN / 8 / 256; ++it) {
                int c = it * 256 + tid;
                int row = c >> 4, col8 = (c & 15) << 3;
                float4 f0 = *(float4*)&Ct[row * 132 + col8];
                float4 f1 = *(float4*)&Ct[row * 132 + col8 + 4];
                union { __bf16 h[8]; float4 v; } u;
                u.h[0] = (__bf16)f0.x; u.h[1] = (__bf16)f0.y; u.h[2] = (__bf16)f0.z; u.h[3] = (__bf16)f0.w;
                u.h[4] = (__bf16)f1.x; u.h[5] = (__bf16)f1.y; u.h[6] = (__bf16)f1.z; u.h[7] = (__bf16)f1.w;
                *(float4*)&outb[(size_t)(bm + row) * N + bn + col8] = u.v;
            }
        } else {
            int col = tid & 127;
            int r0 = (tid >> 7) * 32;
            int gcol = bn - 2048 + col;
            _Float16 buf[32];
            for (int r = 0; r < 32; ++r)
                buf[r] = (_Float16)Ct[(r0 + r) * 132 + col];
            _Float16* dst = &vtout[(size_t)gcol * T_SEQ + bm + r0];
            for (int k = 0; k < 4; ++k)
                *(float4*)&dst[k * 8] = *(float4*)&buf[k * 8];
        }
    } else {
        __bf16* Ct = (__bf16*)smem;
        for (int i = 0; i < NI; ++i)
            for (int j = 0; j < NJ; ++j)
                for (int r = 0; r < 4; ++r) {
                    int row = wm + i * 16 + quad * 4 + r;
                    int col = wn + j * 16 + l16;
                    float v = acc[i][j][r];
                    if (bias) v += bias[bn + col];
                    if (EPI == 1) v = 0.5f * v * (1.f + erff(v * 0.70710678118f));
                    Ct[row * BN + col] = (__bf16)v;
                }
        __syncthreads();
        constexpr int IT = BM * BN / 8 / 256;
        for (int it = 0; it < IT; ++it) {
            int c = it * 256 + tid;
            int row = c >> 4, col = (c & 15) << 3;
            *(float4*)&outb[(size_t)(bm + row) * N + bn + col] = *(float4*)&Ct[row * BN + col];
        }
    }
}

// ---------------- split-K combine. MODE 0: bf16(p0+p1+bias) ----------------
// MODE 2: fp32 p0+p1+bias+resid (+sp scalar write)
template<int MODE>
__global__ __launch_bounds__(256) void combine_kernel(
    const float* __restrict__ p0, const float* __restrict__ p1,
    const float* __restrict__ bias, const float* __restrict__ resid,
    __bf16* __restrict__ outb, float* __restrict__ outf,
    const float* __restrict__ sigacc)
{
    int i = blockIdx.x * 256 + threadIdx.x;
    float4 a = ((const float4*)p0)[i];
    float4 b = ((const float4*)p1)[i];
    int col = (i & 255) << 2;
    float4 bb = *(const float4*)&bias[col];
    float v[4] = {a.x + b.x + bb.x, a.y + b.y + bb.y, a.z + b.z + bb.z, a.w + b.w + bb.w};
    if (MODE == 2) {
        float4 r = ((const float4*)resid)[i];
        v[0] += r.x; v[1] += r.y; v[2] += r.z; v[3] += r.w;
        float4 o = {v[0], v[1], v[2], v[3]};
        ((float4*)outf)[i] = o;
        if (i == 0)
            outf[(size_t)T_SEQ * D_MODEL] = 0.0005f * sigacc[0] * (1.f / 67108864.f);
    } else {
        union { __bf16 h[4]; float2 f2; } u;
        for (int e = 0; e < 4; ++e) u.h[e] = (__bf16)v[e];
        ((float2*)outb)[i] = u.f2;
    }
}

// ---------------- split-K combine + residual + LN2 fused ----------------
__global__ __launch_bounds__(256) void combine_ln_kernel(
    const float* __restrict__ p0, const float* __restrict__ p1,
    const float* __restrict__ resid, const float* __restrict__ g,
    const float* __restrict__ b, float* __restrict__ h_out,
    __bf16* __restrict__ hn_out)
{
    const int t = blockIdx.x, tid = threadIdx.x;
    const int i = t * 256 + tid;
    float4 a = ((const float4*)p0)[i];
    float4 bb = ((const float4*)p1)[i];
    float4 r = ((const float4*)resid)[i];
    float4 v = {a.x + bb.x + r.x, a.y + bb.y + r.y, a.z + bb.z + r.z, a.w + bb.w + r.w};
    ((float4*)h_out)[i] = v;
    float s = v.x + v.y + v.z + v.w;
    float ss = v.x * v.x + v.y * v.y + v.z * v.z + v.w * v.w;
    for (int off = 1; off < 64; off <<= 1) {
        s += __shfl_xor(s, off);
        ss += __shfl_xor(ss, off);
    }
    __shared__ float sb[8];
    int w = tid >> 6, lane = tid & 63;
    if (lane == 0) { sb[w] = s; sb[4 + w] = ss; }
    __syncthreads();
    s = sb[0] + sb[1] + sb[2] + sb[3];
    ss = sb[4] + sb[5] + sb[6] + sb[7];
    float mu = s * (1.f / D_MODEL);
    float var = ss * (1.f / D_MODEL) - mu * mu;
    float rs = rsqrtf(var + 1e-5f);
    const float* vp = (const float*)&v;
    union { __bf16 h[4]; float2 f2; } u;
    for (int k = 0; k < 4; ++k) {
        int d = tid * 4 + k;
        u.h[k] = (__bf16)((vp[k] - mu) * rs * g[d] + b[d]);
    }
    ((float2*)hn_out)[i] = u.f2;
}

// ---------------- split-s dual-variant flash attention ----------------
// Fully software-pipelined: K/V g2l16 AND lmask register loads for chunk i+1
// are issued during chunk i's compute; one barrier per chunk.
__global__ __launch_bounds__(256) void attn_split_kernel(
    const __bf16* __restrict__ qkv, const _Float16* __restrict__ vt,
    const float* __restrict__ lmask,
    __bf16* __restrict__ part_O, float2* __restrict__ part_ml,
    float* __restrict__ sigacc)
{
    __shared__ __bf16 KsAll[2 * 4096];
    __shared__ _Float16 VsAll[2 * 4096];

    const int tid = threadIdx.x;
    const int w = tid >> 6, lane = tid & 63;
    const int quad = lane >> 4, l16 = lane & 15;
    const int idx = blockIdx.x, h = blockIdx.y;
    int qt, sp;
    if (idx < 8)       { qt = idx;                sp = 0; }
    else if (idx < 24) { qt = 8 + ((idx - 8) >> 1);  sp = (idx - 8) & 1; }
    else if (idx < 48) { qt = 16 + (idx - 24) / 3;   sp = (idx - 24) % 3; }
    else               { qt = 24 + ((idx - 48) >> 2); sp = (idx - 48) & 3; }
    const int q0 = qt * 64;
    const int sbeg = sp * 512;
    const int send = min(sbeg + 512, q0 + 64);
    const int nch = (send - sbeg) >> 6;

    const int tq = q0 + w * 16 + l16;

    auto stage = [&](int s0, int bsel) {
        __bf16* kd = &KsAll[bsel * 4096];
        _Float16* vd = &VsAll[bsel * 4096];
        for (int it = 0; it < 2; ++it) {
            int c = it * 256 + tid;
            int tile = c >> 8, c2 = c & 255;
            g2l16(&qkv[(size_t)(s0 + (c2 >> 2)) * QKV_STRIDE + 1024 + h * 64 + tile * 32 + ((c2 & 3) << 3)],
                  &kd[c * 8]);
        }
        for (int it = 0; it < 2; ++it) {
            int c = it * 256 + tid;
            int dh = c >> 3, g = c & 7;
            int sIn = ((g + dh) & 7) * 8;
            g2l16(&vt[((size_t)h * 64 + dh) * T_SEQ + s0 + sIn], &vd[c * 8]);
        }
    };
    auto load_lm = [&](int s0, float4* dst) {
        for (int c = 0; c < 4; ++c)
            dst[c] = *(const float4*)&lmask[((size_t)h * T_SEQ + tq) * T_SEQ + s0 + c * 16 + quad * 4];
    };
    auto load_up = [&](int s0, float4* dst) {
        const float* upp = &lmask[((size_t)h * T_SEQ + s0 + (tid >> 2)) * T_SEQ + q0 + ((tid & 3) << 4)];
        for (int k = 0; k < 4; ++k) dst[k] = *(const float4*)&upp[k * 4];
    };

    bf16x8 qf0 = *(const bf16x8*)&qkv[(size_t)tq * QKV_STRIDE + h * 64 + quad * 8];
    bf16x8 qf1 = *(const bf16x8*)&qkv[(size_t)tq * QKV_STRIDE + h * 64 + 32 + quad * 8];

    float m_[2] = {-1e30f, -1e30f}, l_[2] = {0.f, 0.f};
    f32x4 O[2][4] = {};
    float sigsum = 0.f;

    // prologue: stage chunk 0 + load its lmask tiles
    float4 lmc[4], upc[4], lmn[4], upn[4];
    stage(sbeg, 0);
    load_lm(sbeg, lmc);
    bool lower_c = (sbeg + 64 <= q0);
    if (lower_c) load_up(sbeg, upc);

    for (int ci = 0; ci < nch; ++ci) {
        const int s0 = sbeg + (ci << 6);
        const int cur = ci & 1;
        __syncthreads();   // drains stage(ci)+lm(ci) issued one chunk ago

        const bool has_next = (ci + 1 < nch);
        if (has_next) stage(s0 + 64, cur ^ 1);   // async K/V prefetch

        const __bf16* Ks = &KsAll[cur * 4096];
        const _Float16* Vs = &VsAll[cur * 4096];

        f32x4 St[4];
        for (int c = 0; c < 4; ++c) {
            bf16x8 kf0 = *(const bf16x8*)&Ks[(c * 16 + l16) * 32 + quad * 8];
            bf16x8 kf1 = *(const bf16x8*)&Ks[2048 + (c * 16 + l16) * 32 + quad * 8];
            f32x4 z = {};
            z = MFMA16(kf0, qf0, z);
            z = MFMA16(kf1, qf1, z);
            St[c] = z * 0.125f;
        }
        f16x4 vf[4][4];
        for (int c = 0; c < 4; ++c)
            for (int j = 0; j < 4; ++j) {
                int dh = j * 16 + l16;
                int gg = ((2 * c + (quad >> 1)) - dh) & 7;
                vf[c][j] = *(const f16x4*)&Vs[dh * 64 + gg * 8 + (quad & 1) * 4];
            }

        // lmask prefetch for next chunk (consumed after next barrier)
        bool lower_n = false;
        if (has_next) {
            load_lm(s0 + 64, lmn);
            lower_n = (s0 + 128 <= q0);
            if (lower_n) load_up(s0 + 64, upn);
        }

        if (lower_c)
            for (int k = 0; k < 4; ++k) {
                const float* uu = (const float*)&upc[k];
                sigsum += sigm(uu[0]) + sigm(uu[1]) + sigm(uu[2]) + sigm(uu[3]);
            }
        float sg[4][4];
        for (int c = 0; c < 4; ++c) {
            const float* lp = (const float*)&lmc[c];
            for (int r = 0; r < 4; ++r) { sg[c][r] = sigm(lp[r]); sigsum += sg[c][r]; }
        }

        for (int v = 0; v < 2; ++v) {
            float p[4][4];
            float mx = -1e30f;
            for (int c = 0; c < 4; ++c) {
                int sbase = s0 + c * 16 + quad * 4;
                for (int r = 0; r < 4; ++r) {
                    float val = v ? St[c][r] * sg[c][r] : St[c][r];
                    val = (sbase + r > tq) ? -1e30f : val;
                    p[c][r] = val;
                    mx = fmaxf(mx, val);
                }
            }
            mx = fmaxf(mx, __shfl_xor(mx, 16));
            mx = fmaxf(mx, __shfl_xor(mx, 32));
            float mn = fmaxf(m_[v], mx);
            float al = __expf(m_[v] - mn);
            m_[v] = mn;
            float rs = 0.f;
            f16x4 pa[4];
            for (int c = 0; c < 4; ++c)
                for (int r = 0; r < 4; ++r) {
                    float e = __expf(p[c][r] - mn);
                    rs += e;
                    pa[c][r] = (_Float16)e;
                }
            rs += __shfl_xor(rs, 16);
            rs += __shfl_xor(rs, 32);
            l_[v] = l_[v] * al + rs;
            float alO[4];
            for (int r = 0; r < 4; ++r) alO[r] = bperm(quad * 4 + r, al);
            for (int j = 0; j < 4; ++j)
                for (int r = 0; r < 4; ++r) O[v][j][r] *= alO[r];
            for (int c = 0; c < 4; ++c)
                for (int j = 0; j < 4; ++j)
                    O[v][j] = MFMA16H(pa[c], vf[c][j], O[v][j]);
        }

        // rotate pipeline registers
        for (int c = 0; c < 4; ++c) lmc[c] = lmn[c];
        if (lower_n) for (int k = 0; k < 4; ++k) upc[k] = upn[k];
        lower_c = lower_n;
    }

    const size_t slot = (size_t)h * 80 + idx;
    for (int v = 0; v < 2; ++v)
        for (int j = 0; j < 4; ++j)
            for (int r = 0; r < 4; ++r) {
                int row = w * 16 + quad * 4 + r;
                part_O[((slot * 2 + v) * 64 + row) * 64 + j * 16 + l16] = (__bf16)O[v][j][r];
            }
    if (quad == 0)
        for (int v = 0; v < 2; ++v)
            part_ml[(slot * 2 + v) * 64 + w * 16 + l16] = make_float2(m_[v], l_[v]);
    for (int off = 1; off < 64; off <<= 1) sigsum += __shfl_xor(sigsum, off);
    if (lane == 0) atomicAdd(sigacc, sigsum);
}

// ---------------- combine partials -> cat ----------------
__global__ __launch_bounds__(256) void attn_combine_kernel(
    const __bf16* __restrict__ part_O, const float2* __restrict__ part_ml,
    __bf16* __restrict__ cat)
{
    const int qt = blockIdx.x, h = blockIdx.y;
    const int nsp = (qt >> 3) + 1;
    const int base = (qt < 8) ? qt : (qt < 16) ? 8 + (qt - 8) * 2
                   : (qt < 24) ? 24 + (qt - 16) * 3 : 48 + (qt - 24) * 4;
    const int tid = threadIdx.x;
    const int row = tid >> 2, v = (tid >> 1) & 1, colh = (tid & 1) * 32;

    float2 ml[4];
    float M = -1e30f;
    for (int p = 0; p < nsp; ++p) {
        ml[p] = part_ml[(((size_t)h * 80 + base + p) * 2 + v) * 64 + row];
        M = fmaxf(M, ml[p].x);
    }
    float L = 0.f;
    float acc[32] = {};
    for (int p = 0; p < nsp; ++p) {
        float sc = __expf(ml[p].x - M);
        L += sc * ml[p].y;
        const __bf16* src =
            &part_O[((((size_t)h * 80 + base + p) * 2 + v) * 64 + row) * 64 + colh];
        for (int k = 0; k < 4; ++k) {
            bf16x8 o = *(const bf16x8*)&src[k * 8];
            for (int e = 0; e < 8; ++e) acc[k * 8 + e] += sc * (float)o[e];
        }
    }
    float inv = 1.f / L;
    __bf16* dst = &cat[(size_t)(qt * 64 + row) * 2048 + v * 1024 + h * 64 + colh];
    for (int k = 0; k < 4; ++k) {
        union { __bf16 hh[8]; float4 f4; } u;
        for (int e = 0; e < 8; ++e) u.hh[e] = (__bf16)(acc[k * 8 + e] * inv);
        *(float4*)&dst[k * 8] = u.f4;
    }
}

// ---------------- launch ----------------
extern "C" void kernel_launch(void* const* d_in, const int* in_sizes, int n_in,
                              void* d_out, int out_size, void* d_ws, size_t ws_size,
                              hipStream_t stream)
{
    const float* x      = (const float*)d_in[0];
    const float* W_qkv  = (const float*)d_in[2];
    const float* W_out  = (const float*)d_in[3];
    const float* lmask  = (const float*)d_in[4];
    const float* W_gate = (const float*)d_in[5];
    const float* b_gate = (const float*)d_in[6];
    const float* g1     = (const float*)d_in[7];
    const float* b1     = (const float*)d_in[8];
    const float* g2     = (const float*)d_in[9];
    const float* b2     = (const float*)d_in[10];
    const float* W_ff1  = (const float*)d_in[11];
    const float* b_ff1  = (const float*)d_in[12];
    const float* W_ff2  = (const float*)d_in[13];
    const float* b_ff2  = (const float*)d_in[14];
    float* out = (float*)d_out;

    char* ws = (char*)d_ws;
    size_t off = 0;
    auto alloc = [&](size_t bytes) {
        char* p = ws + off;
        off += (bytes + 255) & ~(size_t)255;
        return p;
    };
    __bf16* wq_b   = (__bf16*)alloc((size_t)3072 * 1024 * 2);
    __bf16* wout_b = (__bf16*)alloc((size_t)1024 * 1024 * 2);
    __bf16* wg_b   = (__bf16*)alloc((size_t)1024 * 2048 * 2);
    __bf16* wf1_b  = (__bf16*)alloc((size_t)4096 * 1024 * 2);
    __bf16* wf2_b  = (__bf16*)alloc((size_t)1024 * 4096 * 2);
    __bf16* xn_b   = (__bf16*)alloc((size_t)2048 * 1024 * 2);
    __bf16* qkv_b  = (__bf16*)alloc((size_t)2048 * 3072 * 2);
    _Float16* vt_h = (_Float16*)alloc((size_t)16 * 64 * 2048 * 2);
    __bf16* cat_b  = (__bf16*)alloc((size_t)2048 * 2048 * 2);
    __bf16* a1_b   = (__bf16*)alloc((size_t)2048 * 1024 * 2);
    float*  h_f    = (float*)alloc((size_t)2048 * 1024 * 4);
    __bf16* hn_b   = (__bf16*)alloc((size_t)2048 * 1024 * 2);
    __bf16* e_b    = (__bf16*)alloc((size_t)2048 * 4096 * 2);
    __bf16* part_O = (__bf16*)alloc((size_t)16 * 80 * 2 * 64 * 64 * 2);
    float2* part_ml= (float2*)alloc((size_t)16 * 80 * 2 * 64 * 8);
    float*  psum   = (float*)alloc((size_t)2 * 2048 * 1024 * 4);
    float*  acc    = (float*)alloc(256);
    float*  psum1  = psum + (size_t)2048 * 1024;

    cast_all_kernel<<<7168, 256, 0, stream>>>(W_qkv, W_out, W_gate, W_ff1, W_ff2,
                                              wq_b, wout_b, wg_b, wf1_b, wf2_b, acc);
    ln_kernel<<<2048, 256, 0, stream>>>(x, g1, b1, xn_b);
    gemm_nt<64, 4><<<dim3(32, 24), 256, 0, stream>>>(xn_b, wq_b, nullptr, qkv_b, nullptr, vt_h, 2048, 3072, 1024, 1024);
    attn_split_kernel<<<dim3(80, 16), 256, 0, stream>>>(qkv_b, vt_h, lmask, part_O, part_ml, acc);
    attn_combine_kernel<<<dim3(32, 16), 256, 0, stream>>>(part_O, part_ml, cat_b);
    gemm_nt<64, 3><<<dim3(32, 8, 2), 256, 0, stream>>>(cat_b, wg_b, nullptr, nullptr, psum, nullptr, 2048, 1024, 1024, 2048);
    combine_kernel<0><<<2048, 256, 0, stream>>>(psum, psum1, b_gate, nullptr, a1_b, nullptr, nullptr);
    gemm_nt<64, 3><<<dim3(32, 8, 2), 256, 0, stream>>>(a1_b, wout_b, nullptr, nullptr, psum, nullptr, 2048, 1024, 512, 1024);
    combine_ln_kernel<<<2048, 256, 0, stream>>>(psum, psum1, x, g2, b2, h_f, hn_b);
    gemm_nt<128, 1><<<dim3(16, 32), 256, 0, stream>>>(hn_b, wf1_b, b_ff1, e_b, nullptr, nullptr, 2048, 4096, 1024, 1024);
    gemm_nt<64, 3><<<dim3(32, 8, 2), 256, 0, stream>>>(e_b, wf2_b, nullptr, nullptr, psum, nullptr, 2048, 1024, 2048, 4096);
    combine_kernel<2><<<2048, 256, 0, stream>>>(psum, psum1, b_ff2, h_f, nullptr, out, acc);

    (void)in_sizes; (void)n_in; (void)out_size; (void)ws_size;
}

// Round 9
// 649.456 us; speedup vs baseline: 1.2599x; 1.0106x over previous
//
#include <hip/hip_runtime.h>
#include <hip/hip_bf16.h>

typedef __bf16 bf16x8 __attribute__((ext_vector_type(8)));
typedef _Float16 f16x4 __attribute__((ext_vector_type(4)));
typedef float f32x4 __attribute__((ext_vector_type(4)));

#define MFMA16(a, b, c) __builtin_amdgcn_mfma_f32_16x16x32_bf16(a, b, c, 0, 0, 0)
#define MFMA16H(a, b, c) __builtin_amdgcn_mfma_f32_16x16x16f16(a, b, c, 0, 0, 0)

#define T_SEQ 2048
#define D_MODEL 1024
#define N_HEADS 16
#define HEAD_DIM 64
#define D_FF 4096
#define QKV_STRIDE 3072

__device__ __forceinline__ float sigm(float x) { return 1.f / (1.f + __expf(-x)); }

__device__ __forceinline__ void g2l16(const void* g, void* l)
{
    __builtin_amdgcn_global_load_lds(
        (const __attribute__((address_space(1))) void*)g,
        (__attribute__((address_space(3))) void*)l, 16, 0, 0);
}

__device__ __forceinline__ float bperm(int srclane, float v)
{
    return __builtin_bit_cast(float,
        __builtin_amdgcn_ds_bpermute(srclane * 4, __builtin_bit_cast(int, v)));
}

// ---------------- fused: all weight casts + LN1 + acc zero ----------------
#define N8_QKV 393216
#define N8_OUT 131072
#define N8_GATE 262144
#define N8_FF1 524288
#define N8_FF2 524288
#define NCAST_BLK 7168
__global__ __launch_bounds__(256) void castln_kernel(
    const float* __restrict__ s0, const float* __restrict__ s1,
    const float* __restrict__ s2, const float* __restrict__ s3,
    const float* __restrict__ s4,
    __bf16* __restrict__ d0, __bf16* __restrict__ d1, __bf16* __restrict__ d2,
    __bf16* __restrict__ d3, __bf16* __restrict__ d4, float* __restrict__ acc,
    const float* __restrict__ x, const float* __restrict__ g,
    const float* __restrict__ b, __bf16* __restrict__ xn)
{
    const int tid = threadIdx.x;
    if (blockIdx.x < NCAST_BLK) {
        int i = blockIdx.x * 256 + tid;
        if (i == 0) acc[0] = 0.f;
        const float* s; __bf16* d; int j;
        if (i < N8_QKV)                           { s = s0; d = d0; j = i; }
        else if (i < N8_QKV + N8_OUT)             { s = s1; d = d1; j = i - N8_QKV; }
        else if (i < N8_QKV + N8_OUT + N8_GATE)   { s = s2; d = d2; j = i - N8_QKV - N8_OUT; }
        else if (i < N8_QKV + N8_OUT + N8_GATE + N8_FF1)
            { s = s3; d = d3; j = i - N8_QKV - N8_OUT - N8_GATE; }
        else { s = s4; d = d4; j = i - N8_QKV - N8_OUT - N8_GATE - N8_FF1; }
        const float4* p = (const float4*)s + (size_t)j * 2;
        float4 a = p[0], bq = p[1];
        union { __bf16 h[8]; float4 v; } u;
        u.h[0] = (__bf16)a.x; u.h[1] = (__bf16)a.y; u.h[2] = (__bf16)a.z; u.h[3] = (__bf16)a.w;
        u.h[4] = (__bf16)bq.x; u.h[5] = (__bf16)bq.y; u.h[6] = (__bf16)bq.z; u.h[7] = (__bf16)bq.w;
        ((float4*)d)[j] = u.v;
        return;
    }
    // LN1 part: one block per row
    const int t = blockIdx.x - NCAST_BLK;
    float4 xv = *(const float4*)&x[t * D_MODEL + tid * 4];
    float s = xv.x + xv.y + xv.z + xv.w;
    float ss = xv.x * xv.x + xv.y * xv.y + xv.z * xv.z + xv.w * xv.w;
    for (int off = 1; off < 64; off <<= 1) {
        s += __shfl_xor(s, off);
        ss += __shfl_xor(ss, off);
    }
    __shared__ float sb[8];
    int w = tid >> 6, lane = tid & 63;
    if (lane == 0) { sb[w] = s; sb[4 + w] = ss; }
    __syncthreads();
    s = sb[0] + sb[1] + sb[2] + sb[3];
    ss = sb[4] + sb[5] + sb[6] + sb[7];
    float mu = s * (1.f / D_MODEL);
    float var = ss * (1.f / D_MODEL) - mu * mu;
    float rs = rsqrtf(var + 1e-5f);
    const float* xp = (const float*)&xv;
    for (int i = 0; i < 4; ++i) {
        int d = tid * 4 + i;
        xn[t * D_MODEL + d] = (__bf16)((xp[i] - mu) * rs * g[d] + b[d]);
    }
}

// ---------------- NT GEMM, BK=64, single-barrier LDS double-buffer ---------
// EPI 1: bias + exact GELU -> bf16; EPI 3: fp32 partial (split-K slice z);
// EPI 4: qkv fused -- bn<2048 normal bf16 store, bn>=2048 transposed f16 -> vt.
template<int BM, int EPI>
__global__ __launch_bounds__(256) void gemm_nt(
    const __bf16* __restrict__ A, const __bf16* __restrict__ B,
    const float* __restrict__ bias,
    __bf16* __restrict__ outb, float* __restrict__ outf, _Float16* __restrict__ vtout,
    int M, int N, int klen, int lda)
{
    constexpr int BN = 128;
    constexpr int SBUF = (BM + BN) * 64 * 2;     // bytes per staging buffer
    constexpr int STAGE = SBUF * 2;              // double-buffered
    constexpr int CTB = (EPI == 3) ? BM * BN * 4 : (EPI == 4) ? BM * 132 * 4 : BM * BN * 2;
    constexpr int SMEM = (STAGE > CTB) ? STAGE : CTB;
    __shared__ __align__(16) char smem[SMEM];

    const int tid = threadIdx.x;
    const int lane = tid & 63, w = tid >> 6;
    const int quad = lane >> 4, l16 = lane & 15;
    const int bm = blockIdx.x * BM, bn = blockIdx.y * BN;
    const int koff = blockIdx.z * klen;
    if (EPI == 3) outf += (size_t)blockIdx.z * M * N;
    constexpr int NI = 4;
    constexpr int NJ = (BM == 128) ? 4 : 2;
    const int wm = (BM == 128) ? (w & 1) * 64 : 0;
    const int wn = (BM == 128) ? (w >> 1) * 64 : w * 32;

    auto stageg = [&](int k0, int b) {
        __bf16* As = (__bf16*)(smem + b * SBUF);
        __bf16* Bs = As + BM * 64;
        constexpr int AIT = BM * 8 / 256;
        for (int it = 0; it < AIT; ++it) {
            int c = it * 256 + tid;
            int tile = (c >= BM * 4) ? 1 : 0;
            int c2 = c & (BM * 4 - 1);
            g2l16(&A[(size_t)(bm + (c2 >> 2)) * lda + koff + k0 + tile * 32 + ((c2 & 3) << 3)],
                  &As[c * 8]);
        }
        for (int it = 0; it < 4; ++it) {
            int c = it * 256 + tid;
            int tile = (c >= 512) ? 1 : 0;
            int c2 = c & 511;
            g2l16(&B[(size_t)(bn + (c2 >> 2)) * lda + koff + k0 + tile * 32 + ((c2 & 3) << 3)],
                  &Bs[c * 8]);
        }
    };

    f32x4 acc[NI][NJ] = {};
    const int nkt = klen >> 6;
    stageg(0, 0);

    for (int kt = 0; kt < nkt; ++kt) {
        __syncthreads();                         // drains stage(kt)
        if (kt + 1 < nkt) stageg((kt + 1) << 6, (kt + 1) & 1);   // async prefetch
        const __bf16* As = (const __bf16*)(smem + (kt & 1) * SBUF);
        const __bf16* Bs = As + BM * 64;
        for (int ks = 0; ks < 2; ++ks) {
            bf16x8 af[NI], bfr[NJ];
            for (int i = 0; i < NI; ++i)
                af[i] = *(const bf16x8*)&As[ks * BM * 32 + (wm + i * 16 + l16) * 32 + quad * 8];
            for (int j = 0; j < NJ; ++j)
                bfr[j] = *(const bf16x8*)&Bs[ks * BN * 32 + (wn + j * 16 + l16) * 32 + quad * 8];
            for (int i = 0; i < NI; ++i)
                for (int j = 0; j < NJ; ++j)
                    acc[i][j] = MFMA16(af[i], bfr[j], acc[i][j]);
        }
    }

    __syncthreads();
    if (EPI == 3) {
        float* Ct = (float*)smem;
        for (int i = 0; i < NI; ++i)
            for (int j = 0; j < NJ; ++j)
                for (int r = 0; r < 4; ++r)
                    Ct[(wm + i * 16 + quad * 4 + r) * BN + wn + j * 16 + l16] = acc[i][j][r];
        __syncthreads();
        constexpr int IT = BM * BN / 4 / 256;
        for (int it = 0; it < IT; ++it) {
            int c = it * 256 + tid;
            int row = c >> 5, col = (c & 31) << 2;
            *(float4*)&outf[(size_t)(bm + row) * N + bn + col] = *(float4*)&Ct[row * BN + col];
        }
    } else if (EPI == 4) {
        float* Ct = (float*)smem;                   // [BM][132] padded fp32
        for (int i = 0; i < NI; ++i)
            for (int j = 0; j < NJ; ++j)
                for (int r = 0; r < 4; ++r)
                    Ct[(wm + i * 16 + quad * 4 + r) * 132 + wn + j * 16 + l16] = acc[i][j][r];
        __syncthreads();
        if (bn < 2048) {
            for (int it = 0; it < BM * BN / 8 / 256; ++it) {
                int c = it * 256 + tid;
                int row = c >> 4, col8 = (c & 15) << 3;
                float4 f0 = *(float4*)&Ct[row * 132 + col8];
                float4 f1 = *(float4*)&Ct[row * 132 + col8 + 4];
                union { __bf16 h[8]; float4 v; } u;
                u.h[0] = (__bf16)f0.x; u.h[1] = (__bf16)f0.y; u.h[2] = (__bf16)f0.z; u.h[3] = (__bf16)f0.w;
                u.h[4] = (__bf16)f1.x; u.h[5] = (__bf16)f1.y; u.h[6] = (__bf16)f1.z; u.h[7] = (__bf16)f1.w;
                *(float4*)&outb[(size_t)(bm + row) * N + bn + col8] = u.v;
            }
        } else {
            int col = tid & 127;
            int r0 = (tid >> 7) * 32;
            int gcol = bn - 2048 + col;
            _Float16 buf[32];
            for (int r = 0; r < 32; ++r)
                buf[r] = (_Float16)Ct[(r0 + r) * 132 + col];
            _Float16* dst = &vtout[(size_t)gcol * T_SEQ + bm + r0];
            for (int k = 0; k < 4; ++k)
                *(float4*)&dst[k * 8] = *(float4*)&buf[k * 8];
        }
    } else {
        __bf16* Ct = (__bf16*)smem;
        for (int i = 0; i < NI; ++i)
            for (int j = 0; j < NJ; ++j)
                for (int r = 0; r < 4; ++r) {
                    int row = wm + i * 16 + quad * 4 + r;
                    int col = wn + j * 16 + l16;
                    float v = acc[i][j][r];
                    if (bias) v += bias[bn + col];
                    if (EPI == 1) v = 0.5f * v * (1.f + erff(v * 0.70710678118f));
                    Ct[row * BN + col] = (__bf16)v;
                }
        __syncthreads();
        constexpr int IT = BM * BN / 8 / 256;
        for (int it = 0; it < IT; ++it) {
            int c = it * 256 + tid;
            int row = c >> 4, col = (c & 15) << 3;
            *(float4*)&outb[(size_t)(bm + row) * N + bn + col] = *(float4*)&Ct[row * BN + col];
        }
    }
}

// ---------------- split-K combine over NP partials (N=1024) ----------------
// MODE 0: bf16(sum+bias); MODE 2: fp32 sum+bias+resid (+sp scalar write)
template<int MODE, int NP>
__global__ __launch_bounds__(256) void combine_kernel(
    const float* __restrict__ ps, const float* __restrict__ bias,
    const float* __restrict__ resid,
    __bf16* __restrict__ outb, float* __restrict__ outf,
    const float* __restrict__ sigacc)
{
    const size_t stride = (size_t)T_SEQ * D_MODEL / 4;   // float4 stride per slice
    int i = blockIdx.x * 256 + threadIdx.x;
    float4 a = ((const float4*)ps)[i];
    float v[4] = {a.x, a.y, a.z, a.w};
    for (int p = 1; p < NP; ++p) {
        float4 bq = ((const float4*)ps)[i + p * stride];
        v[0] += bq.x; v[1] += bq.y; v[2] += bq.z; v[3] += bq.w;
    }
    int col = (i & 255) << 2;
    float4 bb = *(const float4*)&bias[col];
    v[0] += bb.x; v[1] += bb.y; v[2] += bb.z; v[3] += bb.w;
    if (MODE == 2) {
        float4 r = ((const float4*)resid)[i];
        v[0] += r.x; v[1] += r.y; v[2] += r.z; v[3] += r.w;
        float4 o = {v[0], v[1], v[2], v[3]};
        ((float4*)outf)[i] = o;
        if (i == 0)
            outf[(size_t)T_SEQ * D_MODEL] = 0.0005f * sigacc[0] * (1.f / 67108864.f);
    } else {
        union { __bf16 h[4]; float2 f2; } u;
        for (int e = 0; e < 4; ++e) u.h[e] = (__bf16)v[e];
        ((float2*)outb)[i] = u.f2;
    }
}

// ---------------- split-K(2) combine + residual + LN2 fused ----------------
__global__ __launch_bounds__(256) void combine_ln_kernel(
    const float* __restrict__ p0, const float* __restrict__ p1,
    const float* __restrict__ resid, const float* __restrict__ g,
    const float* __restrict__ b, float* __restrict__ h_out,
    __bf16* __restrict__ hn_out)
{
    const int t = blockIdx.x, tid = threadIdx.x;
    const int i = t * 256 + tid;
    float4 a = ((const float4*)p0)[i];
    float4 bb = ((const float4*)p1)[i];
    float4 r = ((const float4*)resid)[i];
    float4 v = {a.x + bb.x + r.x, a.y + bb.y + r.y, a.z + bb.z + r.z, a.w + bb.w + r.w};
    ((float4*)h_out)[i] = v;
    float s = v.x + v.y + v.z + v.w;
    float ss = v.x * v.x + v.y * v.y + v.z * v.z + v.w * v.w;
    for (int off = 1; off < 64; off <<= 1) {
        s += __shfl_xor(s, off);
        ss += __shfl_xor(ss, off);
    }
    __shared__ float sb[8];
    int w = tid >> 6, lane = tid & 63;
    if (lane == 0) { sb[w] = s; sb[4 + w] = ss; }
    __syncthreads();
    s = sb[0] + sb[1] + sb[2] + sb[3];
    ss = sb[4] + sb[5] + sb[6] + sb[7];
    float mu = s * (1.f / D_MODEL);
    float var = ss * (1.f / D_MODEL) - mu * mu;
    float rs = rsqrtf(var + 1e-5f);
    const float* vp = (const float*)&v;
    union { __bf16 h[4]; float2 f2; } u;
    for (int k = 0; k < 4; ++k) {
        int d = tid * 4 + k;
        u.h[k] = (__bf16)((vp[k] - mu) * rs * g[d] + b[d]);
    }
    ((float2*)hn_out)[i] = u.f2;
}

// ---------------- split-s dual-variant flash attention ----------------
__global__ __launch_bounds__(256) void attn_split_kernel(
    const __bf16* __restrict__ qkv, const _Float16* __restrict__ vt,
    const float* __restrict__ lmask,
    __bf16* __restrict__ part_O, float2* __restrict__ part_ml,
    float* __restrict__ sigacc)
{
    __shared__ __bf16 KsAll[2 * 4096];
    __shared__ _Float16 VsAll[2 * 4096];

    const int tid = threadIdx.x;
    const int w = tid >> 6, lane = tid & 63;
    const int quad = lane >> 4, l16 = lane & 15;
    const int idx = blockIdx.x, h = blockIdx.y;
    int qt, sp;
    if (idx < 8)       { qt = idx;                sp = 0; }
    else if (idx < 24) { qt = 8 + ((idx - 8) >> 1);  sp = (idx - 8) & 1; }
    else if (idx < 48) { qt = 16 + (idx - 24) / 3;   sp = (idx - 24) % 3; }
    else               { qt = 24 + ((idx - 48) >> 2); sp = (idx - 48) & 3; }
    const int q0 = qt * 64;
    const int sbeg = sp * 512;
    const int send = min(sbeg + 512, q0 + 64);
    const int nch = (send - sbeg) >> 6;

    const int tq = q0 + w * 16 + l16;

    auto stage = [&](int s0, int bsel) {
        __bf16* kd = &KsAll[bsel * 4096];
        _Float16* vd = &VsAll[bsel * 4096];
        for (int it = 0; it < 2; ++it) {
            int c = it * 256 + tid;
            int tile = c >> 8, c2 = c & 255;
            g2l16(&qkv[(size_t)(s0 + (c2 >> 2)) * QKV_STRIDE + 1024 + h * 64 + tile * 32 + ((c2 & 3) << 3)],
                  &kd[c * 8]);
        }
        for (int it = 0; it < 2; ++it) {
            int c = it * 256 + tid;
            int dh = c >> 3, g = c & 7;
            int sIn = ((g + dh) & 7) * 8;
            g2l16(&vt[((size_t)h * 64 + dh) * T_SEQ + s0 + sIn], &vd[c * 8]);
        }
    };
    auto load_lm = [&](int s0, float4* dst) {
        for (int c = 0; c < 4; ++c)
            dst[c] = *(const float4*)&lmask[((size_t)h * T_SEQ + tq) * T_SEQ + s0 + c * 16 + quad * 4];
    };
    auto load_up = [&](int s0, float4* dst) {
        const float* upp = &lmask[((size_t)h * T_SEQ + s0 + (tid >> 2)) * T_SEQ + q0 + ((tid & 3) << 4)];
        for (int k = 0; k < 4; ++k) dst[k] = *(const float4*)&upp[k * 4];
    };

    bf16x8 qf0 = *(const bf16x8*)&qkv[(size_t)tq * QKV_STRIDE + h * 64 + quad * 8];
    bf16x8 qf1 = *(const bf16x8*)&qkv[(size_t)tq * QKV_STRIDE + h * 64 + 32 + quad * 8];

    float m_[2] = {-1e30f, -1e30f}, l_[2] = {0.f, 0.f};
    f32x4 O[2][4] = {};
    float sigsum = 0.f;

    float4 lmc[4], upc[4], lmn[4], upn[4];
    stage(sbeg, 0);
    load_lm(sbeg, lmc);
    bool lower_c = (sbeg + 64 <= q0);
    if (lower_c) load_up(sbeg, upc);

    for (int ci = 0; ci < nch; ++ci) {
        const int s0 = sbeg + (ci << 6);
        const int cur = ci & 1;
        __syncthreads();

        const bool has_next = (ci + 1 < nch);
        if (has_next) stage(s0 + 64, cur ^ 1);

        const __bf16* Ks = &KsAll[cur * 4096];
        const _Float16* Vs = &VsAll[cur * 4096];

        f32x4 St[4];
        for (int c = 0; c < 4; ++c) {
            bf16x8 kf0 = *(const bf16x8*)&Ks[(c * 16 + l16) * 32 + quad * 8];
            bf16x8 kf1 = *(const bf16x8*)&Ks[2048 + (c * 16 + l16) * 32 + quad * 8];
            f32x4 z = {};
            z = MFMA16(kf0, qf0, z);
            z = MFMA16(kf1, qf1, z);
            St[c] = z * 0.125f;
        }
        f16x4 vf[4][4];
        for (int c = 0; c < 4; ++c)
            for (int j = 0; j < 4; ++j) {
                int dh = j * 16 + l16;
                int gg = ((2 * c + (quad >> 1)) - dh) & 7;
                vf[c][j] = *(const f16x4*)&Vs[dh * 64 + gg * 8 + (quad & 1) * 4];
            }

        bool lower_n = false;
        if (has_next) {
            load_lm(s0 + 64, lmn);
            lower_n = (s0 + 128 <= q0);
            if (lower_n) load_up(s0 + 64, upn);
        }

        if (lower_c)
            for (int k = 0; k < 4; ++k) {
                const float* uu = (const float*)&upc[k];
                sigsum += sigm(uu[0]) + sigm(uu[1]) + sigm(uu[2]) + sigm(uu[3]);
            }
        float sg[4][4];
        for (int c = 0; c < 4; ++c) {
            const float* lp = (const float*)&lmc[c];
            for (int r = 0; r < 4; ++r) { sg[c][r] = sigm(lp[r]); sigsum += sg[c][r]; }
        }

        for (int v = 0; v < 2; ++v) {
            float p[4][4];
            float mx = -1e30f;
            for (int c = 0; c < 4; ++c) {
                int sbase = s0 + c * 16 + quad * 4;
                for (int r = 0; r < 4; ++r) {
                    float val = v ? St[c][r] * sg[c][r] : St[c][r];
                    val = (sbase + r > tq) ? -1e30f : val;
                    p[c][r] = val;
                    mx = fmaxf(mx, val);
                }
            }
            mx = fmaxf(mx, __shfl_xor(mx, 16));
            mx = fmaxf(mx, __shfl_xor(mx, 32));
            float mn = fmaxf(m_[v], mx);
            float al = __expf(m_[v] - mn);
            m_[v] = mn;
            float rs = 0.f;
            f16x4 pa[4];
            for (int c = 0; c < 4; ++c)
                for (int r = 0; r < 4; ++r) {
                    float e = __expf(p[c][r] - mn);
                    rs += e;
                    pa[c][r] = (_Float16)e;
                }
            rs += __shfl_xor(rs, 16);
            rs += __shfl_xor(rs, 32);
            l_[v] = l_[v] * al + rs;
            float alO[4];
            for (int r = 0; r < 4; ++r) alO[r] = bperm(quad * 4 + r, al);
            for (int j = 0; j < 4; ++j)
                for (int r = 0; r < 4; ++r) O[v][j][r] *= alO[r];
            for (int c = 0; c < 4; ++c)
                for (int j = 0; j < 4; ++j)
                    O[v][j] = MFMA16H(pa[c], vf[c][j], O[v][j]);
        }

        for (int c = 0; c < 4; ++c) lmc[c] = lmn[c];
        if (lower_n) for (int k = 0; k < 4; ++k) upc[k] = upn[k];
        lower_c = lower_n;
    }

    const size_t slot = (size_t)h * 80 + idx;
    for (int v = 0; v < 2; ++v)
        for (int j = 0; j < 4; ++j)
            for (int r = 0; r < 4; ++r) {
                int row = w * 16 + quad * 4 + r;
                part_O[((slot * 2 + v) * 64 + row) * 64 + j * 16 + l16] = (__bf16)O[v][j][r];
            }
    if (quad == 0)
        for (int v = 0; v < 2; ++v)
            part_ml[(slot * 2 + v) * 64 + w * 16 + l16] = make_float2(m_[v], l_[v]);
    for (int off = 1; off < 64; off <<= 1) sigsum += __shfl_xor(sigsum, off);
    if (lane == 0) atomicAdd(sigacc, sigsum);
}

// ---------------- combine partials -> cat ----------------
__global__ __launch_bounds__(256) void attn_combine_kernel(
    const __bf16* __restrict__ part_O, const float2* __restrict__ part_ml,
    __bf16* __restrict__ cat)
{
    const int qt = blockIdx.x, h = blockIdx.y;
    const int nsp = (qt >> 3) + 1;
    const int base = (qt < 8) ? qt : (qt < 16) ? 8 + (qt - 8) * 2
                   : (qt < 24) ? 24 + (qt - 16) * 3 : 48 + (qt - 24) * 4;
    const int tid = threadIdx.x;
    const int row = tid >> 2, v = (tid >> 1) & 1, colh = (tid & 1) * 32;

    float2 ml[4];
    float M = -1e30f;
    for (int p = 0; p < nsp; ++p) {
        ml[p] = part_ml[(((size_t)h * 80 + base + p) * 2 + v) * 64 + row];
        M = fmaxf(M, ml[p].x);
    }
    float L = 0.f;
    float acc[32] = {};
    for (int p = 0; p < nsp; ++p) {
        float sc = __expf(ml[p].x - M);
        L += sc * ml[p].y;
        const __bf16* src =
            &part_O[((((size_t)h * 80 + base + p) * 2 + v) * 64 + row) * 64 + colh];
        for (int k = 0; k < 4; ++k) {
            bf16x8 o = *(const bf16x8*)&src[k * 8];
            for (int e = 0; e < 8; ++e) acc[k * 8 + e] += sc * (float)o[e];
        }
    }
    float inv = 1.f / L;
    __bf16* dst = &cat[(size_t)(qt * 64 + row) * 2048 + v * 1024 + h * 64 + colh];
    for (int k = 0; k < 4; ++k) {
        union { __bf16 hh[8]; float4 f4; } u;
        for (int e = 0; e < 8; ++e) u.hh[e] = (__bf16)(acc[k * 8 + e] * inv);
        *(float4*)&dst[k * 8] = u.f4;
    }
}

// ---------------- launch ----------------
extern "C" void kernel_launch(void* const* d_in, const int* in_sizes, int n_in,
                              void* d_out, int out_size, void* d_ws, size_t ws_size,
                              hipStream_t stream)
{
    const float* x      = (const float*)d_in[0];
    const float* W_qkv  = (const float*)d_in[2];
    const float* W_out  = (const float*)d_in[3];
    const float* lmask  = (const float*)d_in[4];
    const float* W_gate = (const float*)d_in[5];
    const float* b_gate = (const float*)d_in[6];
    const float* g1     = (const float*)d_in[7];
    const float* b1     = (const float*)d_in[8];
    const float* g2     = (const float*)d_in[9];
    const float* b2     = (const float*)d_in[10];
    const float* W_ff1  = (const float*)d_in[11];
    const float* b_ff1  = (const float*)d_in[12];
    const float* W_ff2  = (const float*)d_in[13];
    const float* b_ff2  = (const float*)d_in[14];
    float* out = (float*)d_out;

    char* ws = (char*)d_ws;
    size_t off = 0;
    auto alloc = [&](size_t bytes) {
        char* p = ws + off;
        off += (bytes + 255) & ~(size_t)255;
        return p;
    };
    __bf16* wq_b   = (__bf16*)alloc((size_t)3072 * 1024 * 2);
    __bf16* wout_b = (__bf16*)alloc((size_t)1024 * 1024 * 2);
    __bf16* wg_b   = (__bf16*)alloc((size_t)1024 * 2048 * 2);
    __bf16* wf1_b  = (__bf16*)alloc((size_t)4096 * 1024 * 2);
    __bf16* wf2_b  = (__bf16*)alloc((size_t)1024 * 4096 * 2);
    __bf16* xn_b   = (__bf16*)alloc((size_t)2048 * 1024 * 2);
    __bf16* qkv_b  = (__bf16*)alloc((size_t)2048 * 3072 * 2);
    _Float16* vt_h = (_Float16*)alloc((size_t)16 * 64 * 2048 * 2);
    __bf16* cat_b  = (__bf16*)alloc((size_t)2048 * 2048 * 2);
    __bf16* a1_b   = (__bf16*)alloc((size_t)2048 * 1024 * 2);
    float*  h_f    = (float*)alloc((size_t)2048 * 1024 * 4);
    __bf16* hn_b   = (__bf16*)alloc((size_t)2048 * 1024 * 2);
    __bf16* e_b    = (__bf16*)alloc((size_t)2048 * 4096 * 2);
    __bf16* part_O = (__bf16*)alloc((size_t)16 * 80 * 2 * 64 * 64 * 2);
    float2* part_ml= (float2*)alloc((size_t)16 * 80 * 2 * 64 * 8);
    float*  psum   = (float*)alloc((size_t)4 * 2048 * 1024 * 4);   // up to 4 slices
    float*  acc    = (float*)alloc(256);
    float*  psum1  = psum + (size_t)2048 * 1024;

    // 1. casts + LN1 (+acc zero)
    castln_kernel<<<NCAST_BLK + 2048, 256, 0, stream>>>(
        W_qkv, W_out, W_gate, W_ff1, W_ff2,
        wq_b, wout_b, wg_b, wf1_b, wf2_b, acc, x, g1, b1, xn_b);
    // 2. qkv GEMM (fused V transpose)
    gemm_nt<64, 4><<<dim3(32, 24), 256, 0, stream>>>(xn_b, wq_b, nullptr, qkv_b, nullptr, vt_h, 2048, 3072, 1024, 1024);
    // 3. attention (fused sigmoid-sum)
    attn_split_kernel<<<dim3(80, 16), 256, 0, stream>>>(qkv_b, vt_h, lmask, part_O, part_ml, acc);
    // 4. attention combine -> cat
    attn_combine_kernel<<<dim3(32, 16), 256, 0, stream>>>(part_O, part_ml, cat_b);
    // 5-6. gate: 128x128 tile, split-K=4 (klen 512) + combine4
    gemm_nt<128, 3><<<dim3(16, 8, 4), 256, 0, stream>>>(cat_b, wg_b, nullptr, nullptr, psum, nullptr, 2048, 1024, 512, 2048);
    combine_kernel<0, 4><<<2048, 256, 0, stream>>>(psum, b_gate, nullptr, a1_b, nullptr, nullptr);
    // 7-8. out-proj: BM=64 split-K=2 + combine+resid+LN2
    gemm_nt<64, 3><<<dim3(32, 8, 2), 256, 0, stream>>>(a1_b, wout_b, nullptr, nullptr, psum, nullptr, 2048, 1024, 512, 1024);
    combine_ln_kernel<<<2048, 256, 0, stream>>>(psum, psum1, x, g2, b2, h_f, hn_b);
    // 9. ff1 + GELU
    gemm_nt<128, 1><<<dim3(16, 32), 256, 0, stream>>>(hn_b, wf1_b, b_ff1, e_b, nullptr, nullptr, 2048, 4096, 1024, 1024);
    // 10-11. ff2: 128x128 tile, split-K=4 (klen 1024) + combine4 (+sp write)
    gemm_nt<128, 3><<<dim3(16, 8, 4), 256, 0, stream>>>(e_b, wf2_b, nullptr, nullptr, psum, nullptr, 2048, 1024, 1024, 4096);
    combine_kernel<2, 4><<<2048, 256, 0, stream>>>(psum, b_ff2, h_f, nullptr, out, acc);

    (void)in_sizes; (void)n_in; (void)out_size; (void)ws_size;
}